// Round 1
// 550.841 us; speedup vs baseline: 1.0080x; 1.0080x over previous
//
#include <hip/hip_runtime.h>
#include <math.h>

#define N   200000
#define E   6400000
#define IN_ 128
#define D   16
#define G   1024
#define BNEPS 1e-5f

#define BSH   9                      // 512 cols per bucket
#define NBKT  391                    // ceil(N / 512)
#define CH    8192                   // edges per k_bin block
#define BINB  782                    // ceil(E / CH)

typedef _Float16 f16;
typedef __attribute__((ext_vector_type(8))) _Float16 f16x8;
typedef __attribute__((ext_vector_type(4))) float f32x4;
typedef __attribute__((ext_vector_type(2))) float f32x2;

// ---------- helpers ----------
__device__ __forceinline__ unsigned f2ord(float f) {
    unsigned b = __float_as_uint(f);
    return (b & 0x80000000u) ? ~b : (b | 0x80000000u);
}
__device__ __forceinline__ float ord2f(unsigned u) {
    return __uint_as_float((u & 0x80000000u) ? (u & 0x7FFFFFFFu) : ~u);
}
// f32 -> fp8 e4m3 (OCP on gfx950), single byte
__device__ __forceinline__ unsigned char f2fp8(float v) {
    return (unsigned char)(__builtin_amdgcn_cvt_pk_fp8_f32(v, v, 0, false) & 0xFF);
}
__device__ __forceinline__ float fp82f(unsigned char b) {
    return __builtin_amdgcn_cvt_f32_fp8((unsigned)b, 0);
}

// ---------- bucket histogram ----------
__global__ __launch_bounds__(256) void k_hist(const int* __restrict__ col,
                                              unsigned* __restrict__ bucketCnt) {
    __shared__ unsigned h[NBKT];
    for (int i = threadIdx.x; i < NBKT; i += 256) h[i] = 0u;
    __syncthreads();
    int stride = gridDim.x * 256;
    for (int e = blockIdx.x * 256 + threadIdx.x; e < E; e += stride)
        atomicAdd(&h[col[e] >> BSH], 1u);
    __syncthreads();
    for (int i = threadIdx.x; i < NBKT; i += 256)
        if (h[i]) atomicAdd(&bucketCnt[i], h[i]);
}

// ---------- scan bucket counts ----------
__global__ __launch_bounds__(512) void k_bscan(const unsigned* __restrict__ bucketCnt,
                                               unsigned* __restrict__ bucketBase,
                                               unsigned* __restrict__ cursorB,
                                               unsigned* __restrict__ rowptr) {
    __shared__ unsigned s[512];
    int t = threadIdx.x;
    s[t] = (t < NBKT) ? bucketCnt[t] : 0u;
    __syncthreads();
    for (int off = 1; off < 512; off <<= 1) {
        unsigned v = (t >= off) ? s[t - off] : 0u;
        __syncthreads();
        s[t] += v;
        __syncthreads();
    }
    unsigned excl = (t > 0) ? s[t - 1] : 0u;
    if (t <= NBKT) {
        bucketBase[t] = excl;
        cursorB[t] = excl;
    }
    if (t == 0) rowptr[N] = E;
}

// ---------- phase 1: bin edges by bucket ----------
__global__ __launch_bounds__(512) void k_bin(const int* __restrict__ row,
                                             const int* __restrict__ col,
                                             unsigned* __restrict__ cursorB,
                                             unsigned* __restrict__ tmp) {
    __shared__ unsigned hist[512];   // after scan phase: lbase
    __shared__ unsigned offs[512];   // inclusive scan (lbase[b+1])
    __shared__ unsigned lcur[512];
    __shared__ unsigned gbase[512];
    __shared__ unsigned sbuf[CH];    // 32 KB
    int tid = threadIdx.x;
    int base = blockIdx.x * CH;
    int cnt = min(CH, E - base);
    hist[tid] = 0u;
    __syncthreads();
    for (int i = tid; i < cnt; i += 512)
        atomicAdd(&hist[col[base + i] >> BSH], 1u);
    __syncthreads();
    offs[tid] = hist[tid];
    __syncthreads();
    for (int off = 1; off < 512; off <<= 1) {
        unsigned v = (tid >= off) ? offs[tid - off] : 0u;
        __syncthreads();
        offs[tid] += v;
        __syncthreads();
    }
    unsigned lb = (tid > 0) ? offs[tid - 1] : 0u;
    unsigned c0 = offs[tid] - lb;
    lcur[tid] = lb;
    hist[tid] = lb;   // hist now holds lbase
    if (tid < NBKT && c0) gbase[tid] = atomicAdd(&cursorB[tid], c0);
    __syncthreads();
    for (int i = tid; i < cnt; i += 512) {
        int c = col[base + i];
        int r = row[base + i];
        int b = c >> BSH;
        unsigned p = atomicAdd(&lcur[b], 1u);
        sbuf[p] = (unsigned)r | ((unsigned)(c & ((1 << BSH) - 1)) << 18);
    }
    __syncthreads();
    // bucket-major coalesced copy-out: one wave per bucket
    int wv = tid >> 6, ln = tid & 63;
    for (int b = wv; b < NBKT; b += 8) {
        unsigned l0 = hist[b], l1 = offs[b], gb = gbase[b];
        for (unsigned i2 = l0 + ln; i2 < l1; i2 += 64)
            tmp[gb + (i2 - l0)] = sbuf[i2];
    }
}

// ---------- phase 2: per-bucket counting sort ----------
__global__ __launch_bounds__(512) void k_bsort(const unsigned* __restrict__ bucketBase,
                                               const unsigned* __restrict__ tmp,
                                               unsigned* __restrict__ rowptr,
                                               float* __restrict__ dis,
                                               int* __restrict__ srcA) {
    __shared__ unsigned cnt[512];
    __shared__ unsigned offs[512];
    __shared__ unsigned lcur[512];
    int tid = threadIdx.x;
    int b = blockIdx.x;
    unsigned s0 = bucketBase[b], s1 = bucketBase[b + 1];
    cnt[tid] = 0u;
    __syncthreads();
    for (unsigned i = s0 + tid; i < s1; i += 512)
        atomicAdd(&cnt[tmp[i] >> 18], 1u);
    __syncthreads();
    offs[tid] = cnt[tid];
    __syncthreads();
    for (int off = 1; off < 512; off <<= 1) {
        unsigned v = (tid >= off) ? offs[tid - off] : 0u;
        __syncthreads();
        offs[tid] += v;
        __syncthreads();
    }
    unsigned excl = (tid > 0) ? offs[tid - 1] : 0u;
    int c = (b << BSH) + tid;
    if (c < N) {
        rowptr[c] = s0 + excl;
        dis[c] = rsqrtf((float)cnt[tid] + 1.0f);
    }
    lcur[tid] = s0 + excl;
    __syncthreads();
    for (unsigned i = s0 + tid; i < s1; i += 512) {
        unsigned p = tmp[i];
        unsigned pos = atomicAdd(&lcur[p >> 18], 1u);
        srcA[pos] = (int)(p & 0x3FFFFu);
    }
}

// ---------- hs1 = fp8((x @ W1) * dis) via MFMA 16x16x32 f16 ----------
__global__ __launch_bounds__(256) void k_gemm1(const float* __restrict__ x,
                                               const float* __restrict__ W1,
                                               const float* __restrict__ dis,
                                               unsigned char* __restrict__ hs) {
    __shared__ f16 Wh[IN_ * D];
    int tid = threadIdx.x;
    for (int i = tid; i < IN_ * D; i += 256) Wh[i] = (f16)W1[i];
    __syncthreads();
    int lane = tid & 63;
    int wave = tid >> 6;
    int m = lane & 15, quad = lane >> 4;
    f16x8 bfrag[4];
#pragma unroll
    for (int s = 0; s < 4; s++)
#pragma unroll
        for (int jj = 0; jj < 8; jj++)
            bfrag[s][jj] = Wh[(s * 32 + quad * 8 + jj) * D + m];
    int gwave = blockIdx.x * 4 + wave;
    int nwaves = gridDim.x * 4;
    const int ntiles = N / 16;
    for (int t = gwave; t < ntiles; t += nwaves) {
        int n0 = t * 16;
        const float* xrow = x + (size_t)(n0 + m) * IN_ + quad * 8;
        f32x4 acc = {0.f, 0.f, 0.f, 0.f};
#pragma unroll
        for (int s = 0; s < 4; s++) {
            float4 lo = *(const float4*)(xrow + s * 32);
            float4 hi = *(const float4*)(xrow + s * 32 + 4);
            f16x8 a;
            a[0] = (f16)lo.x; a[1] = (f16)lo.y; a[2] = (f16)lo.z; a[3] = (f16)lo.w;
            a[4] = (f16)hi.x; a[5] = (f16)hi.y; a[6] = (f16)hi.z; a[7] = (f16)hi.w;
            acc = __builtin_amdgcn_mfma_f32_16x16x32_f16(a, bfrag[s], acc, 0, 0, 0);
        }
#pragma unroll
        for (int r = 0; r < 4; r++) {
            int rowi = n0 + quad * 4 + r;
            hs[(size_t)rowi * D + m] = f2fp8(acc[r] * dis[rowi]);
        }
    }
}

// ---------- wide gather core (fp8 table): sums 16 features of CSR segment ----------
// 16 lanes per node: lane j -> feature j. Table row = 16 bytes fp8 e4m3.
__device__ __forceinline__ float gather_row_sum(const unsigned* __restrict__ rowptr,
                                                const int* __restrict__ srcA,
                                                const unsigned char* __restrict__ hs,
                                                int i, int j, float seed) {
    unsigned start = rowptr[i], end = rowptr[i + 1];
    unsigned len = end - start;
    unsigned nfull = len & ~7u;
    int es = j >> 1;          // edge slot 0..7
    int half = j & 1;         // which 8-feature half
    float acc[8] = {0.f, 0.f, 0.f, 0.f, 0.f, 0.f, 0.f, 0.f};
    for (unsigned off = 0; off < nfull; off += 8) {
        int idx = __builtin_nontemporal_load(&srcA[start + off + (j & 7)]);
        int src = __shfl(idx, es, 16);
        uint2 v = *(const uint2*)(hs + ((size_t)src << 4) + (half << 3));
        f32x2 f0 = __builtin_amdgcn_cvt_pk_f32_fp8(v.x, false);
        f32x2 f1 = __builtin_amdgcn_cvt_pk_f32_fp8(v.x, true);
        f32x2 f2 = __builtin_amdgcn_cvt_pk_f32_fp8(v.y, false);
        f32x2 f3 = __builtin_amdgcn_cvt_pk_f32_fp8(v.y, true);
        acc[0] += f0.x; acc[1] += f0.y; acc[2] += f1.x; acc[3] += f1.y;
        acc[4] += f2.x; acc[5] += f2.y; acc[6] += f3.x; acc[7] += f3.y;
    }
    // butterfly over edge-slot bits (keep half fixed)
#pragma unroll
    for (int mask = 2; mask <= 8; mask <<= 1) {
#pragma unroll
        for (int k = 0; k < 8; k++) acc[k] += __shfl_xor(acc[k], mask, 16);
    }
    // redistribute: lane j wants acc[j&7] from lane (j>>3) (lane0=half0, lane1=half1)
    float x = 0.f;
    int srcl = j >> 3;
#pragma unroll
    for (int k = 0; k < 8; k++) {
        float vk = __shfl(acc[k], srcl, 16);
        if ((j & 7) == k) x = vk;
    }
    // tail (<8 edges) scalar path
    float xt = seed;
    for (unsigned e = start + nfull; e < end; e++) {
        int src = srcA[e];
        xt += fp82f(hs[((size_t)src << 4) + j]);
    }
    return x + xt;
}

// ---------- layer1 gather + BN1/ReLU + GEMM2 ----------
__global__ __launch_bounds__(256) void k_gather1(const unsigned* __restrict__ rowptr,
                                                 const int* __restrict__ srcA,
                                                 const float* __restrict__ dis,
                                                 const unsigned char* __restrict__ hs1,
                                                 const float* __restrict__ b1,
                                                 const float* __restrict__ g1,
                                                 const float* __restrict__ be1,
                                                 const float* __restrict__ m1,
                                                 const float* __restrict__ v1,
                                                 const float* __restrict__ W2,
                                                 unsigned char* __restrict__ hs2) {
    __shared__ float W2s[D * D];
    int tid = threadIdx.x;
    if (tid < D * D) W2s[tid] = W2[tid];
    __syncthreads();
    int i = blockIdx.x * 16 + (tid >> 4);
    int j = tid & 15;
    float self = fp82f(hs1[((size_t)i << 4) + j]);
    float sum = gather_row_sum(rowptr, srcA, hs1, i, j, self);
    float di = dis[i];
    float tt = di * sum + b1[j];
    tt = fmaxf(tt, 0.f);
    float sc = g1[j] * rsqrtf(v1[j] + BNEPS);
    float x1 = (tt - m1[j]) * sc + be1[j];
    float acc = 0.f;
#pragma unroll
    for (int kk = 0; kk < D; kk++) {
        float v = __shfl(x1, kk, 16);
        acc += v * W2s[kk * D + j];
    }
    hs2[((size_t)i << 4) + j] = f2fp8(acc * di);
}

// ---------- layer2 gather + BN2/ReLU ----------
__global__ __launch_bounds__(256) void k_gather2(const unsigned* __restrict__ rowptr,
                                                 const int* __restrict__ srcA,
                                                 const float* __restrict__ dis,
                                                 const unsigned char* __restrict__ hs2,
                                                 const float* __restrict__ b2,
                                                 const float* __restrict__ g2,
                                                 const float* __restrict__ be2,
                                                 const float* __restrict__ m2,
                                                 const float* __restrict__ v2,
                                                 f16* __restrict__ x2) {
    int tid = threadIdx.x;
    int i = blockIdx.x * 16 + (tid >> 4);
    int j = tid & 15;
    float self = fp82f(hs2[((size_t)i << 4) + j]);
    float sum = gather_row_sum(rowptr, srcA, hs2, i, j, self);
    float tt = dis[i] * sum + b2[j];
    tt = fmaxf(tt, 0.f);
    float sc = g2[j] * rsqrtf(v2[j] + BNEPS);
    x2[((size_t)i << 4) + j] = (f16)((tt - m2[j]) * sc + be2[j]);
}

// ---------- pooling ----------
__global__ __launch_bounds__(256) void k_pool(const f16* __restrict__ x2,
                                              const int* __restrict__ batch,
                                              unsigned* __restrict__ gmaxT,
                                              float* __restrict__ gsum,
                                              unsigned* __restrict__ gcnt) {
    __shared__ unsigned smax[32 * D];
    __shared__ float ssum[32 * D];
    __shared__ unsigned scnt[32];
    int tid = threadIdx.x;
    for (int s = tid; s < 32 * D; s += 256) { smax[s] = 0u; ssum[s] = 0.f; }
    if (tid < 32) scnt[tid] = 0u;
    __syncthreads();
    int n = blockIdx.x * 256 + tid;
    int g0 = batch[blockIdx.x * 256];
    if (n < N) {
        int lg = batch[n] - g0;
        const f16* xp = x2 + (size_t)n * D;
        if (lg < 32) {
            atomicAdd(&scnt[lg], 1u);
#pragma unroll
            for (int j = 0; j < D; j++) {
                float v = (float)xp[j];
                atomicMax(&smax[lg * D + j], f2ord(v));
                atomicAdd(&ssum[lg * D + j], v);
            }
        } else {
            int g = batch[n];
            atomicAdd(&gcnt[g], 1u);
#pragma unroll
            for (int j = 0; j < D; j++) {
                float v = (float)xp[j];
                atomicMax(&gmaxT[(size_t)g * D + j], f2ord(v));
                atomicAdd(&gsum[(size_t)g * D + j], v);
            }
        }
    }
    __syncthreads();
    for (int s = tid; s < 32 * D; s += 256) {
        int slot = s >> 4, j = s & 15;
        if (scnt[slot] > 0u) {
            int g = g0 + slot;
            atomicMax(&gmaxT[(size_t)g * D + j], smax[s]);
            atomicAdd(&gsum[(size_t)g * D + j], ssum[s]);
            if (j == 0) atomicAdd(&gcnt[g], scnt[slot]);
        }
    }
}

// ---------- head ----------
__global__ __launch_bounds__(256) void k_head(const unsigned* __restrict__ gmaxT,
                                              const float* __restrict__ gsum,
                                              const unsigned* __restrict__ gcnt,
                                              const float* __restrict__ Wb,
                                              const float* __restrict__ bb,
                                              const float* __restrict__ Wm,
                                              const float* __restrict__ bm,
                                              float* __restrict__ out) {
    __shared__ float Wbs[32 * 16];
    __shared__ float bbs[16], Wms[16];
    __shared__ float bm0;
    int tid = threadIdx.x;
    for (int i = tid; i < 32 * 16; i += 256) Wbs[i] = Wb[i];
    if (tid < 16) { bbs[tid] = bb[tid]; Wms[tid] = Wm[tid]; }
    if (tid == 0) bm0 = bm[0];
    __syncthreads();
    int g = blockIdx.x * 256 + tid;
    if (g >= G) return;
    float in[32];
    float inv = 1.0f / (float)gcnt[g];
#pragma unroll
    for (int j = 0; j < D; j++) {
        in[j] = ord2f(gmaxT[(size_t)g * D + j]);
        in[16 + j] = gsum[(size_t)g * D + j] * inv;
    }
    float z = bm0;
#pragma unroll
    for (int j = 0; j < 16; j++) {
        float acc = bbs[j];
#pragma unroll
        for (int k = 0; k < 32; k++) acc += in[k] * Wbs[k * 16 + j];
        acc = fmaxf(acc, 0.f);
        z += acc * Wms[j];
    }
    out[g] = 1.0f / (1.0f + expf(-z));
}

extern "C" void kernel_launch(void* const* d_in, const int* in_sizes, int n_in,
                              void* d_out, int out_size, void* d_ws, size_t ws_size,
                              hipStream_t stream) {
    const float* x   = (const float*)d_in[0];
    const int* ei    = (const int*)d_in[1];
    const int* rowp  = ei;
    const int* colp  = ei + E;
    const int* batch = (const int*)d_in[2];
    const float* W1  = (const float*)d_in[3];
    const float* b1  = (const float*)d_in[4];
    const float* g1  = (const float*)d_in[5];
    const float* be1 = (const float*)d_in[6];
    const float* m1  = (const float*)d_in[7];
    const float* v1  = (const float*)d_in[8];
    const float* W2  = (const float*)d_in[9];
    const float* b2  = (const float*)d_in[10];
    const float* g2  = (const float*)d_in[11];
    const float* be2 = (const float*)d_in[12];
    const float* m2  = (const float*)d_in[13];
    const float* v2  = (const float*)d_in[14];
    const float* Wb  = (const float*)d_in[15];
    const float* bb  = (const float*)d_in[16];
    const float* Wm  = (const float*)d_in[17];
    const float* bm  = (const float*)d_in[18];
    float* out = (float*)d_out;

    char* ws = (char*)d_ws;
    int*      srcA   = (int*)     (ws);                // E i32            [0, 25.6M)
    unsigned* tmp    = (unsigned*)(ws + 25600000);     // E u32 packed     [25.6M, 51.2M)
    unsigned char* hs1 = (unsigned char*)(ws + 25600000); // N*D fp8 (3.2MB) — overlays tmp AFTER k_bsort
    unsigned char* hs2 = (unsigned char*)(ws + 28800000); // N*D fp8 (3.2MB) — also in dead tmp area
    f16*      x2buf  = (f16*)     (ws + 32000000);     // N*D f16 (6.4MB)
    unsigned* rowptr = (unsigned*)(ws + 51200000);     // (N+1) u32
    float*    dis    = (float*)   (ws + 52000016);     // N f32
    unsigned* bucketCnt  = (unsigned*)(ws + 52800016);
    unsigned* bucketBase = (unsigned*)(ws + 52801600);
    unsigned* cursorB    = (unsigned*)(ws + 52803200);
    unsigned* gmaxT  = (unsigned*)(ws + 52804800);
    float*    gsum   = (float*)   (ws + 52870336);
    unsigned* gcnt   = (unsigned*)(ws + 52935872);

    const int NB = (N + 255) / 256;

    hipMemsetAsync(bucketCnt, 0, (NBKT + 1) * 4, stream);
    hipMemsetAsync(gmaxT, 0, (size_t)G * D * 4, stream);
    hipMemsetAsync(gsum, 0, (size_t)G * D * 4, stream);
    hipMemsetAsync(gcnt, 0, (size_t)G * 4, stream);

    k_hist<<<1024, 256, 0, stream>>>(colp, bucketCnt);
    k_bscan<<<1, 512, 0, stream>>>(bucketCnt, bucketBase, cursorB, rowptr);
    k_bin<<<BINB, 512, 0, stream>>>(rowp, colp, cursorB, tmp);
    k_bsort<<<NBKT, 512, 0, stream>>>(bucketBase, tmp, rowptr, dis, srcA);

    k_gemm1<<<512, 256, 0, stream>>>(x, W1, dis, hs1);

    k_gather1<<<N / 16, 256, 0, stream>>>(rowptr, srcA, dis, hs1,
                                          b1, g1, be1, m1, v1, W2, hs2);
    k_gather2<<<N / 16, 256, 0, stream>>>(rowptr, srcA, dis, hs2,
                                          b2, g2, be2, m2, v2, x2buf);

    k_pool<<<NB, 256, 0, stream>>>(x2buf, batch, gmaxT, gsum, gcnt);
    k_head<<<(G + 255) / 256, 256, 0, stream>>>(gmaxT, gsum, gcnt, Wb, bb, Wm, bm, out);
}

// Round 2
// 491.488 us; speedup vs baseline: 1.1297x; 1.1208x over previous
//
#include <hip/hip_runtime.h>
#include <math.h>

#define N   200000
#define E   6400000
#define IN_ 128
#define D   16
#define G   1024
#define BNEPS 1e-5f

#define BSH   9                      // 512 cols per bucket
#define NBKT  391                    // ceil(N / 512)
#define CH    8192                   // edges per k_bin block
#define BINB  782                    // ceil(E / CH)

typedef _Float16 f16;
typedef __attribute__((ext_vector_type(8))) _Float16 f16x8;
typedef __attribute__((ext_vector_type(4))) float f32x4;
typedef __attribute__((ext_vector_type(2))) float f32x2;

// ---------- helpers ----------
__device__ __forceinline__ unsigned f2ord(float f) {
    unsigned b = __float_as_uint(f);
    return (b & 0x80000000u) ? ~b : (b | 0x80000000u);
}
__device__ __forceinline__ float ord2f(unsigned u) {
    return __uint_as_float((u & 0x80000000u) ? (u & 0x7FFFFFFFu) : ~u);
}
// f32 -> fp8 e4m3 (OCP on gfx950), single byte
__device__ __forceinline__ unsigned char f2fp8(float v) {
    return (unsigned char)(__builtin_amdgcn_cvt_pk_fp8_f32(v, v, 0, false) & 0xFF);
}
__device__ __forceinline__ float fp82f(unsigned char b) {
    return __builtin_amdgcn_cvt_f32_fp8((unsigned)b, 0);
}

// ---------- bucket histogram ----------
__global__ __launch_bounds__(256) void k_hist(const int* __restrict__ col,
                                              unsigned* __restrict__ bucketCnt) {
    __shared__ unsigned h[NBKT];
    for (int i = threadIdx.x; i < NBKT; i += 256) h[i] = 0u;
    __syncthreads();
    int stride = gridDim.x * 256;
    for (int e = blockIdx.x * 256 + threadIdx.x; e < E; e += stride)
        atomicAdd(&h[col[e] >> BSH], 1u);
    __syncthreads();
    for (int i = threadIdx.x; i < NBKT; i += 256)
        if (h[i]) atomicAdd(&bucketCnt[i], h[i]);
}

// ---------- scan bucket counts ----------
__global__ __launch_bounds__(512) void k_bscan(const unsigned* __restrict__ bucketCnt,
                                               unsigned* __restrict__ bucketBase,
                                               unsigned* __restrict__ cursorB,
                                               unsigned* __restrict__ rowptr) {
    __shared__ unsigned s[512];
    int t = threadIdx.x;
    s[t] = (t < NBKT) ? bucketCnt[t] : 0u;
    __syncthreads();
    for (int off = 1; off < 512; off <<= 1) {
        unsigned v = (t >= off) ? s[t - off] : 0u;
        __syncthreads();
        s[t] += v;
        __syncthreads();
    }
    unsigned excl = (t > 0) ? s[t - 1] : 0u;
    if (t <= NBKT) {
        bucketBase[t] = excl;
        cursorB[t] = excl;
    }
    if (t == 0) rowptr[N] = E;
}

// ---------- phase 1: bin edges by bucket ----------
__global__ __launch_bounds__(512) void k_bin(const int* __restrict__ row,
                                             const int* __restrict__ col,
                                             unsigned* __restrict__ cursorB,
                                             unsigned* __restrict__ tmp) {
    __shared__ unsigned hist[512];   // after scan phase: lbase
    __shared__ unsigned offs[512];   // inclusive scan (lbase[b+1])
    __shared__ unsigned lcur[512];
    __shared__ unsigned gbase[512];
    __shared__ unsigned sbuf[CH];    // 32 KB
    int tid = threadIdx.x;
    int base = blockIdx.x * CH;
    int cnt = min(CH, E - base);
    hist[tid] = 0u;
    __syncthreads();
    for (int i = tid; i < cnt; i += 512)
        atomicAdd(&hist[col[base + i] >> BSH], 1u);
    __syncthreads();
    offs[tid] = hist[tid];
    __syncthreads();
    for (int off = 1; off < 512; off <<= 1) {
        unsigned v = (tid >= off) ? offs[tid - off] : 0u;
        __syncthreads();
        offs[tid] += v;
        __syncthreads();
    }
    unsigned lb = (tid > 0) ? offs[tid - 1] : 0u;
    unsigned c0 = offs[tid] - lb;
    lcur[tid] = lb;
    hist[tid] = lb;   // hist now holds lbase
    if (tid < NBKT && c0) gbase[tid] = atomicAdd(&cursorB[tid], c0);
    __syncthreads();
    for (int i = tid; i < cnt; i += 512) {
        int c = col[base + i];
        int r = row[base + i];
        int b = c >> BSH;
        unsigned p = atomicAdd(&lcur[b], 1u);
        sbuf[p] = (unsigned)r | ((unsigned)(c & ((1 << BSH) - 1)) << 18);
    }
    __syncthreads();
    // bucket-major coalesced copy-out: one wave per bucket
    int wv = tid >> 6, ln = tid & 63;
    for (int b = wv; b < NBKT; b += 8) {
        unsigned l0 = hist[b], l1 = offs[b], gb = gbase[b];
        for (unsigned i2 = l0 + ln; i2 < l1; i2 += 64)
            tmp[gb + (i2 - l0)] = sbuf[i2];
    }
}

// ---------- phase 2: per-bucket counting sort ----------
__global__ __launch_bounds__(512) void k_bsort(const unsigned* __restrict__ bucketBase,
                                               const unsigned* __restrict__ tmp,
                                               unsigned* __restrict__ rowptr,
                                               float* __restrict__ dis,
                                               int* __restrict__ srcA) {
    __shared__ unsigned cnt[512];
    __shared__ unsigned offs[512];
    __shared__ unsigned lcur[512];
    int tid = threadIdx.x;
    int b = blockIdx.x;
    unsigned s0 = bucketBase[b], s1 = bucketBase[b + 1];
    cnt[tid] = 0u;
    __syncthreads();
    for (unsigned i = s0 + tid; i < s1; i += 512)
        atomicAdd(&cnt[tmp[i] >> 18], 1u);
    __syncthreads();
    offs[tid] = cnt[tid];
    __syncthreads();
    for (int off = 1; off < 512; off <<= 1) {
        unsigned v = (tid >= off) ? offs[tid - off] : 0u;
        __syncthreads();
        offs[tid] += v;
        __syncthreads();
    }
    unsigned excl = (tid > 0) ? offs[tid - 1] : 0u;
    int c = (b << BSH) + tid;
    if (c < N) {
        rowptr[c] = s0 + excl;
        dis[c] = rsqrtf((float)cnt[tid] + 1.0f);
    }
    lcur[tid] = s0 + excl;
    __syncthreads();
    for (unsigned i = s0 + tid; i < s1; i += 512) {
        unsigned p = tmp[i];
        unsigned pos = atomicAdd(&lcur[p >> 18], 1u);
        srcA[pos] = (int)(p & 0x3FFFFu);
    }
}

// ---------- hs1 = fp8((x @ W1) * dis) via MFMA 16x16x32 f16 ----------
__global__ __launch_bounds__(256) void k_gemm1(const float* __restrict__ x,
                                               const float* __restrict__ W1,
                                               const float* __restrict__ dis,
                                               unsigned char* __restrict__ hs) {
    __shared__ f16 Wh[IN_ * D];
    int tid = threadIdx.x;
    for (int i = tid; i < IN_ * D; i += 256) Wh[i] = (f16)W1[i];
    __syncthreads();
    int lane = tid & 63;
    int wave = tid >> 6;
    int m = lane & 15, quad = lane >> 4;
    f16x8 bfrag[4];
#pragma unroll
    for (int s = 0; s < 4; s++)
#pragma unroll
        for (int jj = 0; jj < 8; jj++)
            bfrag[s][jj] = Wh[(s * 32 + quad * 8 + jj) * D + m];
    int gwave = blockIdx.x * 4 + wave;
    int nwaves = gridDim.x * 4;
    const int ntiles = N / 16;
    for (int t = gwave; t < ntiles; t += nwaves) {
        int n0 = t * 16;
        const float* xrow = x + (size_t)(n0 + m) * IN_ + quad * 8;
        f32x4 acc = {0.f, 0.f, 0.f, 0.f};
#pragma unroll
        for (int s = 0; s < 4; s++) {
            float4 lo = *(const float4*)(xrow + s * 32);
            float4 hi = *(const float4*)(xrow + s * 32 + 4);
            f16x8 a;
            a[0] = (f16)lo.x; a[1] = (f16)lo.y; a[2] = (f16)lo.z; a[3] = (f16)lo.w;
            a[4] = (f16)hi.x; a[5] = (f16)hi.y; a[6] = (f16)hi.z; a[7] = (f16)hi.w;
            acc = __builtin_amdgcn_mfma_f32_16x16x32_f16(a, bfrag[s], acc, 0, 0, 0);
        }
#pragma unroll
        for (int r = 0; r < 4; r++) {
            int rowi = n0 + quad * 4 + r;
            hs[(size_t)rowi * D + m] = f2fp8(acc[r] * dis[rowi]);
        }
    }
}

// ---------- wide gather core (fp8 table, full-row-per-lane) ----------
// 16 lanes per node. Each lane loads one edge's FULL 16-byte row per iter
// (1 divergent address per edge), accumulates all 16 features in registers.
// srcA for the next iteration is prefetched so its latency hides under the
// current gather. Remainder edges handled by predication (no serial tail).
// Epilogue: reduce-and-split butterfly transposes so lane j = feature j.
__device__ __forceinline__ float gather_row_sum(const unsigned* __restrict__ rowptr,
                                                const int* __restrict__ srcA,
                                                const unsigned char* __restrict__ hs,
                                                int i, int j, float seed) {
    unsigned start = rowptr[i], end = rowptr[i + 1];
    float acc[16];
#pragma unroll
    for (int k = 0; k < 16; k++) acc[k] = 0.f;
    bool val = (start + (unsigned)j) < end;
    int src = 0;
    if (val) src = __builtin_nontemporal_load(&srcA[start + j]);
    for (unsigned base = start; base < end; base += 16) {
        bool nval = (base + 16u + (unsigned)j) < end;
        int nsrc = 0;
        if (nval) nsrc = __builtin_nontemporal_load(&srcA[base + 16 + j]);
        if (val) {
            uint4 v = *(const uint4*)(hs + ((size_t)src << 4));
            f32x2 f;
            f = __builtin_amdgcn_cvt_pk_f32_fp8(v.x, false); acc[0] += f.x;  acc[1] += f.y;
            f = __builtin_amdgcn_cvt_pk_f32_fp8(v.x, true);  acc[2] += f.x;  acc[3] += f.y;
            f = __builtin_amdgcn_cvt_pk_f32_fp8(v.y, false); acc[4] += f.x;  acc[5] += f.y;
            f = __builtin_amdgcn_cvt_pk_f32_fp8(v.y, true);  acc[6] += f.x;  acc[7] += f.y;
            f = __builtin_amdgcn_cvt_pk_f32_fp8(v.z, false); acc[8] += f.x;  acc[9] += f.y;
            f = __builtin_amdgcn_cvt_pk_f32_fp8(v.z, true);  acc[10] += f.x; acc[11] += f.y;
            f = __builtin_amdgcn_cvt_pk_f32_fp8(v.w, false); acc[12] += f.x; acc[13] += f.y;
            f = __builtin_amdgcn_cvt_pk_f32_fp8(v.w, true);  acc[14] += f.x; acc[15] += f.y;
        }
        val = nval;
        src = nsrc;
    }
    // reduce-and-split butterfly: 15 shfl + 15 add, static reg indices only
    float r8[8];
#pragma unroll
    for (int k = 0; k < 8; k++) {
        float keep = (j & 8) ? acc[k + 8] : acc[k];
        float give = (j & 8) ? acc[k] : acc[k + 8];
        r8[k] = keep + __shfl_xor(give, 8, 16);
    }
    float r4[4];
#pragma unroll
    for (int k = 0; k < 4; k++) {
        float keep = (j & 4) ? r8[k + 4] : r8[k];
        float give = (j & 4) ? r8[k] : r8[k + 4];
        r4[k] = keep + __shfl_xor(give, 4, 16);
    }
    float r2[2];
#pragma unroll
    for (int k = 0; k < 2; k++) {
        float keep = (j & 2) ? r4[k + 2] : r4[k];
        float give = (j & 2) ? r4[k] : r4[k + 2];
        r2[k] = keep + __shfl_xor(give, 2, 16);
    }
    float keep = (j & 1) ? r2[1] : r2[0];
    float give = (j & 1) ? r2[0] : r2[1];
    float x = keep + __shfl_xor(give, 1, 16);
    return x + seed;
}

// ---------- layer1 gather + BN1/ReLU + GEMM2 ----------
__global__ __launch_bounds__(256) void k_gather1(const unsigned* __restrict__ rowptr,
                                                 const int* __restrict__ srcA,
                                                 const float* __restrict__ dis,
                                                 const unsigned char* __restrict__ hs1,
                                                 const float* __restrict__ b1,
                                                 const float* __restrict__ g1,
                                                 const float* __restrict__ be1,
                                                 const float* __restrict__ m1,
                                                 const float* __restrict__ v1,
                                                 const float* __restrict__ W2,
                                                 unsigned char* __restrict__ hs2) {
    __shared__ float W2s[D * D];
    int tid = threadIdx.x;
    if (tid < D * D) W2s[tid] = W2[tid];
    __syncthreads();
    int i = blockIdx.x * 16 + (tid >> 4);
    int j = tid & 15;
    float self = fp82f(hs1[((size_t)i << 4) + j]);
    float sum = gather_row_sum(rowptr, srcA, hs1, i, j, self);
    float di = dis[i];
    float tt = di * sum + b1[j];
    tt = fmaxf(tt, 0.f);
    float sc = g1[j] * rsqrtf(v1[j] + BNEPS);
    float x1 = (tt - m1[j]) * sc + be1[j];
    float acc = 0.f;
#pragma unroll
    for (int kk = 0; kk < D; kk++) {
        float v = __shfl(x1, kk, 16);
        acc += v * W2s[kk * D + j];
    }
    hs2[((size_t)i << 4) + j] = f2fp8(acc * di);
}

// ---------- layer2 gather + BN2/ReLU ----------
__global__ __launch_bounds__(256) void k_gather2(const unsigned* __restrict__ rowptr,
                                                 const int* __restrict__ srcA,
                                                 const float* __restrict__ dis,
                                                 const unsigned char* __restrict__ hs2,
                                                 const float* __restrict__ b2,
                                                 const float* __restrict__ g2,
                                                 const float* __restrict__ be2,
                                                 const float* __restrict__ m2,
                                                 const float* __restrict__ v2,
                                                 f16* __restrict__ x2) {
    int tid = threadIdx.x;
    int i = blockIdx.x * 16 + (tid >> 4);
    int j = tid & 15;
    float self = fp82f(hs2[((size_t)i << 4) + j]);
    float sum = gather_row_sum(rowptr, srcA, hs2, i, j, self);
    float tt = dis[i] * sum + b2[j];
    tt = fmaxf(tt, 0.f);
    float sc = g2[j] * rsqrtf(v2[j] + BNEPS);
    x2[((size_t)i << 4) + j] = (f16)((tt - m2[j]) * sc + be2[j]);
}

// ---------- pooling ----------
__global__ __launch_bounds__(256) void k_pool(const f16* __restrict__ x2,
                                              const int* __restrict__ batch,
                                              unsigned* __restrict__ gmaxT,
                                              float* __restrict__ gsum,
                                              unsigned* __restrict__ gcnt) {
    __shared__ unsigned smax[32 * D];
    __shared__ float ssum[32 * D];
    __shared__ unsigned scnt[32];
    int tid = threadIdx.x;
    for (int s = tid; s < 32 * D; s += 256) { smax[s] = 0u; ssum[s] = 0.f; }
    if (tid < 32) scnt[tid] = 0u;
    __syncthreads();
    int n = blockIdx.x * 256 + tid;
    int g0 = batch[blockIdx.x * 256];
    if (n < N) {
        int lg = batch[n] - g0;
        const f16* xp = x2 + (size_t)n * D;
        if (lg < 32) {
            atomicAdd(&scnt[lg], 1u);
#pragma unroll
            for (int j = 0; j < D; j++) {
                float v = (float)xp[j];
                atomicMax(&smax[lg * D + j], f2ord(v));
                atomicAdd(&ssum[lg * D + j], v);
            }
        } else {
            int g = batch[n];
            atomicAdd(&gcnt[g], 1u);
#pragma unroll
            for (int j = 0; j < D; j++) {
                float v = (float)xp[j];
                atomicMax(&gmaxT[(size_t)g * D + j], f2ord(v));
                atomicAdd(&gsum[(size_t)g * D + j], v);
            }
        }
    }
    __syncthreads();
    for (int s = tid; s < 32 * D; s += 256) {
        int slot = s >> 4, j = s & 15;
        if (scnt[slot] > 0u) {
            int g = g0 + slot;
            atomicMax(&gmaxT[(size_t)g * D + j], smax[s]);
            atomicAdd(&gsum[(size_t)g * D + j], ssum[s]);
            if (j == 0) atomicAdd(&gcnt[g], scnt[slot]);
        }
    }
}

// ---------- head ----------
__global__ __launch_bounds__(256) void k_head(const unsigned* __restrict__ gmaxT,
                                              const float* __restrict__ gsum,
                                              const unsigned* __restrict__ gcnt,
                                              const float* __restrict__ Wb,
                                              const float* __restrict__ bb,
                                              const float* __restrict__ Wm,
                                              const float* __restrict__ bm,
                                              float* __restrict__ out) {
    __shared__ float Wbs[32 * 16];
    __shared__ float bbs[16], Wms[16];
    __shared__ float bm0;
    int tid = threadIdx.x;
    for (int i = tid; i < 32 * 16; i += 256) Wbs[i] = Wb[i];
    if (tid < 16) { bbs[tid] = bb[tid]; Wms[tid] = Wm[tid]; }
    if (tid == 0) bm0 = bm[0];
    __syncthreads();
    int g = blockIdx.x * 256 + tid;
    if (g >= G) return;
    float in[32];
    float inv = 1.0f / (float)gcnt[g];
#pragma unroll
    for (int j = 0; j < D; j++) {
        in[j] = ord2f(gmaxT[(size_t)g * D + j]);
        in[16 + j] = gsum[(size_t)g * D + j] * inv;
    }
    float z = bm0;
#pragma unroll
    for (int j = 0; j < 16; j++) {
        float acc = bbs[j];
#pragma unroll
        for (int k = 0; k < 32; k++) acc += in[k] * Wbs[k * 16 + j];
        acc = fmaxf(acc, 0.f);
        z += acc * Wms[j];
    }
    out[g] = 1.0f / (1.0f + expf(-z));
}

extern "C" void kernel_launch(void* const* d_in, const int* in_sizes, int n_in,
                              void* d_out, int out_size, void* d_ws, size_t ws_size,
                              hipStream_t stream) {
    const float* x   = (const float*)d_in[0];
    const int* ei    = (const int*)d_in[1];
    const int* rowp  = ei;
    const int* colp  = ei + E;
    const int* batch = (const int*)d_in[2];
    const float* W1  = (const float*)d_in[3];
    const float* b1  = (const float*)d_in[4];
    const float* g1  = (const float*)d_in[5];
    const float* be1 = (const float*)d_in[6];
    const float* m1  = (const float*)d_in[7];
    const float* v1  = (const float*)d_in[8];
    const float* W2  = (const float*)d_in[9];
    const float* b2  = (const float*)d_in[10];
    const float* g2  = (const float*)d_in[11];
    const float* be2 = (const float*)d_in[12];
    const float* m2  = (const float*)d_in[13];
    const float* v2  = (const float*)d_in[14];
    const float* Wb  = (const float*)d_in[15];
    const float* bb  = (const float*)d_in[16];
    const float* Wm  = (const float*)d_in[17];
    const float* bm  = (const float*)d_in[18];
    float* out = (float*)d_out;

    char* ws = (char*)d_ws;
    int*      srcA   = (int*)     (ws);                // E i32            [0, 25.6M)
    unsigned* tmp    = (unsigned*)(ws + 25600000);     // E u32 packed     [25.6M, 51.2M)
    unsigned char* hs1 = (unsigned char*)(ws + 25600000); // N*D fp8 (3.2MB) — overlays tmp AFTER k_bsort
    unsigned char* hs2 = (unsigned char*)(ws + 28800000); // N*D fp8 (3.2MB) — also in dead tmp area
    f16*      x2buf  = (f16*)     (ws + 32000000);     // N*D f16 (6.4MB)
    unsigned* rowptr = (unsigned*)(ws + 51200000);     // (N+1) u32
    float*    dis    = (float*)   (ws + 52000016);     // N f32
    unsigned* bucketCnt  = (unsigned*)(ws + 52800016);
    unsigned* bucketBase = (unsigned*)(ws + 52801600);
    unsigned* cursorB    = (unsigned*)(ws + 52803200);
    unsigned* gmaxT  = (unsigned*)(ws + 52804800);
    float*    gsum   = (float*)   (ws + 52870336);
    unsigned* gcnt   = (unsigned*)(ws + 52935872);

    const int NB = (N + 255) / 256;

    hipMemsetAsync(bucketCnt, 0, (NBKT + 1) * 4, stream);
    hipMemsetAsync(gmaxT, 0, (size_t)G * D * 4, stream);
    hipMemsetAsync(gsum, 0, (size_t)G * D * 4, stream);
    hipMemsetAsync(gcnt, 0, (size_t)G * 4, stream);

    k_hist<<<1024, 256, 0, stream>>>(colp, bucketCnt);
    k_bscan<<<1, 512, 0, stream>>>(bucketCnt, bucketBase, cursorB, rowptr);
    k_bin<<<BINB, 512, 0, stream>>>(rowp, colp, cursorB, tmp);
    k_bsort<<<NBKT, 512, 0, stream>>>(bucketBase, tmp, rowptr, dis, srcA);

    k_gemm1<<<512, 256, 0, stream>>>(x, W1, dis, hs1);

    k_gather1<<<N / 16, 256, 0, stream>>>(rowptr, srcA, dis, hs1,
                                          b1, g1, be1, m1, v1, W2, hs2);
    k_gather2<<<N / 16, 256, 0, stream>>>(rowptr, srcA, dis, hs2,
                                          b2, g2, be2, m2, v2, x2buf);

    k_pool<<<NB, 256, 0, stream>>>(x2buf, batch, gmaxT, gsum, gcnt);
    k_head<<<(G + 255) / 256, 256, 0, stream>>>(gmaxT, gsum, gcnt, Wb, bb, Wm, bm, out);
}

// Round 4
// 463.944 us; speedup vs baseline: 1.1968x; 1.0594x over previous
//
#include <hip/hip_runtime.h>
#include <math.h>

#define N   200000
#define E   6400000
#define IN_ 128
#define D   16
#define G   1024
#define BNEPS 1e-5f

#define BSH   9                      // 512 cols per bucket
#define NBKT  391                    // ceil(N / 512)
#define CH    8192                   // edges per k_bin block
#define BINB  782                    // ceil(E / CH)
#define BCAP  18432                  // LDS staging capacity for one bucket (72 KB)

typedef _Float16 f16;
typedef __attribute__((ext_vector_type(8))) _Float16 f16x8;
typedef __attribute__((ext_vector_type(4))) float f32x4;
typedef __attribute__((ext_vector_type(2))) float f32x2;

// ---------- helpers ----------
__device__ __forceinline__ unsigned f2ord(float f) {
    unsigned b = __float_as_uint(f);
    return (b & 0x80000000u) ? ~b : (b | 0x80000000u);
}
__device__ __forceinline__ float ord2f(unsigned u) {
    return __uint_as_float((u & 0x80000000u) ? (u & 0x7FFFFFFFu) : ~u);
}
// f32 -> fp8 e4m3 (OCP on gfx950), single byte
__device__ __forceinline__ unsigned char f2fp8(float v) {
    return (unsigned char)(__builtin_amdgcn_cvt_pk_fp8_f32(v, v, 0, false) & 0xFF);
}
__device__ __forceinline__ float fp82f(unsigned char b) {
    return __builtin_amdgcn_cvt_f32_fp8((unsigned)b, 0);
}

// ---------- bucket histogram ----------
__global__ __launch_bounds__(256) void k_hist(const int* __restrict__ col,
                                              unsigned* __restrict__ bucketCnt) {
    __shared__ unsigned h[NBKT];
    for (int i = threadIdx.x; i < NBKT; i += 256) h[i] = 0u;
    __syncthreads();
    int stride = gridDim.x * 256;
    for (int e = blockIdx.x * 256 + threadIdx.x; e < E; e += stride)
        atomicAdd(&h[col[e] >> BSH], 1u);
    __syncthreads();
    for (int i = threadIdx.x; i < NBKT; i += 256)
        if (h[i]) atomicAdd(&bucketCnt[i], h[i]);
}

// ---------- scan bucket counts ----------
__global__ __launch_bounds__(512) void k_bscan(const unsigned* __restrict__ bucketCnt,
                                               unsigned* __restrict__ bucketBase,
                                               unsigned* __restrict__ cursorB,
                                               unsigned* __restrict__ rowptr) {
    __shared__ unsigned s[512];
    int t = threadIdx.x;
    s[t] = (t < NBKT) ? bucketCnt[t] : 0u;
    __syncthreads();
    for (int off = 1; off < 512; off <<= 1) {
        unsigned v = (t >= off) ? s[t - off] : 0u;
        __syncthreads();
        s[t] += v;
        __syncthreads();
    }
    unsigned excl = (t > 0) ? s[t - 1] : 0u;
    if (t <= NBKT) {
        bucketBase[t] = excl;
        cursorB[t] = excl;
    }
    if (t == 0) rowptr[N] = E;
}

// ---------- phase 1: bin edges by bucket ----------
__global__ __launch_bounds__(512) void k_bin(const int* __restrict__ row,
                                             const int* __restrict__ col,
                                             unsigned* __restrict__ cursorB,
                                             unsigned* __restrict__ tmp) {
    __shared__ unsigned hist[512];   // after scan phase: lbase
    __shared__ unsigned offs[512];   // inclusive scan (lbase[b+1])
    __shared__ unsigned lcur[512];
    __shared__ unsigned gbase[512];
    __shared__ unsigned sbuf[CH];    // 32 KB
    int tid = threadIdx.x;
    int base = blockIdx.x * CH;
    int cnt = min(CH, E - base);
    hist[tid] = 0u;
    __syncthreads();
    for (int i = tid; i < cnt; i += 512)
        atomicAdd(&hist[col[base + i] >> BSH], 1u);
    __syncthreads();
    offs[tid] = hist[tid];
    __syncthreads();
    for (int off = 1; off < 512; off <<= 1) {
        unsigned v = (tid >= off) ? offs[tid - off] : 0u;
        __syncthreads();
        offs[tid] += v;
        __syncthreads();
    }
    unsigned lb = (tid > 0) ? offs[tid - 1] : 0u;
    unsigned c0 = offs[tid] - lb;
    lcur[tid] = lb;
    hist[tid] = lb;   // hist now holds lbase
    if (tid < NBKT && c0) gbase[tid] = atomicAdd(&cursorB[tid], c0);
    __syncthreads();
    for (int i = tid; i < cnt; i += 512) {
        int c = col[base + i];
        int r = row[base + i];
        int b = c >> BSH;
        unsigned p = atomicAdd(&lcur[b], 1u);
        sbuf[p] = (unsigned)r | ((unsigned)(c & ((1 << BSH) - 1)) << 18);
    }
    __syncthreads();
    // bucket-major coalesced copy-out: one wave per bucket
    int wv = tid >> 6, ln = tid & 63;
    for (int b = wv; b < NBKT; b += 8) {
        unsigned l0 = hist[b], l1 = offs[b], gb = gbase[b];
        for (unsigned i2 = l0 + ln; i2 < l1; i2 += 64)
            tmp[gb + (i2 - l0)] = sbuf[i2];
    }
}

// ---------- phase 2: per-bucket counting sort (LDS-staged coalesced output) ----------
__global__ __launch_bounds__(512) void k_bsort(const unsigned* __restrict__ bucketBase,
                                               const unsigned* __restrict__ tmp,
                                               unsigned* __restrict__ rowptr,
                                               float* __restrict__ dis,
                                               int* __restrict__ srcA) {
    __shared__ unsigned cnt[512];
    __shared__ unsigned offs[512];
    __shared__ unsigned lcur[512];
    __shared__ unsigned sout[BCAP];  // 72 KB staging: scatter here, stream out coalesced
    int tid = threadIdx.x;
    int b = blockIdx.x;
    unsigned s0 = bucketBase[b], s1 = bucketBase[b + 1];
    cnt[tid] = 0u;
    __syncthreads();
    for (unsigned i = s0 + tid; i < s1; i += 512)
        atomicAdd(&cnt[tmp[i] >> 18], 1u);
    __syncthreads();
    offs[tid] = cnt[tid];
    __syncthreads();
    for (int off = 1; off < 512; off <<= 1) {
        unsigned v = (tid >= off) ? offs[tid - off] : 0u;
        __syncthreads();
        offs[tid] += v;
        __syncthreads();
    }
    unsigned excl = (tid > 0) ? offs[tid - 1] : 0u;
    int c = (b << BSH) + tid;
    if (c < N) {
        rowptr[c] = s0 + excl;
        dis[c] = rsqrtf((float)cnt[tid] + 1.0f);
    }
    unsigned cap = s1 - s0;
    if (cap <= (unsigned)BCAP) {
        lcur[tid] = excl;                       // bucket-local offsets
        __syncthreads();
        for (unsigned i = s0 + tid; i < s1; i += 512) {
            unsigned p = tmp[i];
            unsigned pos = atomicAdd(&lcur[p >> 18], 1u);
            sout[pos] = p & 0x3FFFFu;
        }
        __syncthreads();
        // coalesced contiguous copy-out
        for (unsigned i = tid; i < cap; i += 512)
            srcA[s0 + i] = (int)sout[i];
    } else {
        // statistically-unreachable fallback: direct global scatter
        lcur[tid] = s0 + excl;
        __syncthreads();
        for (unsigned i = s0 + tid; i < s1; i += 512) {
            unsigned p = tmp[i];
            unsigned pos = atomicAdd(&lcur[p >> 18], 1u);
            srcA[pos] = (int)(p & 0x3FFFFu);
        }
    }
}

// ---------- hs1 = fp8((x @ W1) * dis) via MFMA 16x16x32 f16 ----------
__global__ __launch_bounds__(256) void k_gemm1(const float* __restrict__ x,
                                               const float* __restrict__ W1,
                                               const float* __restrict__ dis,
                                               unsigned char* __restrict__ hs) {
    __shared__ f16 Wh[IN_ * D];
    int tid = threadIdx.x;
    for (int i = tid; i < IN_ * D; i += 256) Wh[i] = (f16)W1[i];
    __syncthreads();
    int lane = tid & 63;
    int wave = tid >> 6;
    int m = lane & 15, quad = lane >> 4;
    f16x8 bfrag[4];
#pragma unroll
    for (int s = 0; s < 4; s++)
#pragma unroll
        for (int jj = 0; jj < 8; jj++)
            bfrag[s][jj] = Wh[(s * 32 + quad * 8 + jj) * D + m];
    int gwave = blockIdx.x * 4 + wave;
    int nwaves = gridDim.x * 4;
    const int ntiles = N / 16;
    for (int t = gwave; t < ntiles; t += nwaves) {
        int n0 = t * 16;
        const float* xrow = x + (size_t)(n0 + m) * IN_ + quad * 8;
        f32x4 acc = {0.f, 0.f, 0.f, 0.f};
#pragma unroll
        for (int s = 0; s < 4; s++) {
            float4 lo = *(const float4*)(xrow + s * 32);
            float4 hi = *(const float4*)(xrow + s * 32 + 4);
            f16x8 a;
            a[0] = (f16)lo.x; a[1] = (f16)lo.y; a[2] = (f16)lo.z; a[3] = (f16)lo.w;
            a[4] = (f16)hi.x; a[5] = (f16)hi.y; a[6] = (f16)hi.z; a[7] = (f16)hi.w;
            acc = __builtin_amdgcn_mfma_f32_16x16x32_f16(a, bfrag[s], acc, 0, 0, 0);
        }
#pragma unroll
        for (int r = 0; r < 4; r++) {
            int rowi = n0 + quad * 4 + r;
            hs[(size_t)rowi * D + m] = f2fp8(acc[r] * dis[rowi]);
        }
    }
}

// ---------- wide gather core (fp8 table, full-row-per-lane) ----------
// 16 lanes per node. Each lane loads one edge's FULL 16-byte row per iter
// (1 divergent address per edge), accumulates all 16 features in registers.
// srcA for the next iteration is prefetched so its latency hides under the
// current gather. Remainder edges handled by predication (no serial tail).
// Epilogue: reduce-and-split butterfly transposes so lane j = feature j.
__device__ __forceinline__ float gather_row_sum(const unsigned* __restrict__ rowptr,
                                                const int* __restrict__ srcA,
                                                const unsigned char* __restrict__ hs,
                                                int i, int j, float seed) {
    unsigned start = rowptr[i], end = rowptr[i + 1];
    float acc[16];
#pragma unroll
    for (int k = 0; k < 16; k++) acc[k] = 0.f;
    bool val = (start + (unsigned)j) < end;
    int src = 0;
    if (val) src = __builtin_nontemporal_load(&srcA[start + j]);
    for (unsigned base = start; base < end; base += 16) {
        bool nval = (base + 16u + (unsigned)j) < end;
        int nsrc = 0;
        if (nval) nsrc = __builtin_nontemporal_load(&srcA[base + 16 + j]);
        if (val) {
            uint4 v = *(const uint4*)(hs + ((size_t)src << 4));
            f32x2 f;
            f = __builtin_amdgcn_cvt_pk_f32_fp8(v.x, false); acc[0] += f.x;  acc[1] += f.y;
            f = __builtin_amdgcn_cvt_pk_f32_fp8(v.x, true);  acc[2] += f.x;  acc[3] += f.y;
            f = __builtin_amdgcn_cvt_pk_f32_fp8(v.y, false); acc[4] += f.x;  acc[5] += f.y;
            f = __builtin_amdgcn_cvt_pk_f32_fp8(v.y, true);  acc[6] += f.x;  acc[7] += f.y;
            f = __builtin_amdgcn_cvt_pk_f32_fp8(v.z, false); acc[8] += f.x;  acc[9] += f.y;
            f = __builtin_amdgcn_cvt_pk_f32_fp8(v.z, true);  acc[10] += f.x; acc[11] += f.y;
            f = __builtin_amdgcn_cvt_pk_f32_fp8(v.w, false); acc[12] += f.x; acc[13] += f.y;
            f = __builtin_amdgcn_cvt_pk_f32_fp8(v.w, true);  acc[14] += f.x; acc[15] += f.y;
        }
        val = nval;
        src = nsrc;
    }
    // reduce-and-split butterfly: 15 shfl + 15 add, static reg indices only
    float r8[8];
#pragma unroll
    for (int k = 0; k < 8; k++) {
        float keep = (j & 8) ? acc[k + 8] : acc[k];
        float give = (j & 8) ? acc[k] : acc[k + 8];
        r8[k] = keep + __shfl_xor(give, 8, 16);
    }
    float r4[4];
#pragma unroll
    for (int k = 0; k < 4; k++) {
        float keep = (j & 4) ? r8[k + 4] : r8[k];
        float give = (j & 4) ? r8[k] : r8[k + 4];
        r4[k] = keep + __shfl_xor(give, 4, 16);
    }
    float r2[2];
#pragma unroll
    for (int k = 0; k < 2; k++) {
        float keep = (j & 2) ? r4[k + 2] : r4[k];
        float give = (j & 2) ? r4[k] : r4[k + 2];
        r2[k] = keep + __shfl_xor(give, 2, 16);
    }
    float keep = (j & 1) ? r2[1] : r2[0];
    float give = (j & 1) ? r2[0] : r2[1];
    float x = keep + __shfl_xor(give, 1, 16);
    return x + seed;
}

// ---------- layer1 gather + BN1/ReLU + GEMM2 ----------
__global__ __launch_bounds__(256) void k_gather1(const unsigned* __restrict__ rowptr,
                                                 const int* __restrict__ srcA,
                                                 const float* __restrict__ dis,
                                                 const unsigned char* __restrict__ hs1,
                                                 const float* __restrict__ b1,
                                                 const float* __restrict__ g1,
                                                 const float* __restrict__ be1,
                                                 const float* __restrict__ m1,
                                                 const float* __restrict__ v1,
                                                 const float* __restrict__ W2,
                                                 unsigned char* __restrict__ hs2) {
    __shared__ float W2s[D * D];
    int tid = threadIdx.x;
    if (tid < D * D) W2s[tid] = W2[tid];
    __syncthreads();
    int i = blockIdx.x * 16 + (tid >> 4);
    int j = tid & 15;
    float self = fp82f(hs1[((size_t)i << 4) + j]);
    float sum = gather_row_sum(rowptr, srcA, hs1, i, j, self);
    float di = dis[i];
    float tt = di * sum + b1[j];
    tt = fmaxf(tt, 0.f);
    float sc = g1[j] * rsqrtf(v1[j] + BNEPS);
    float x1 = (tt - m1[j]) * sc + be1[j];
    float acc = 0.f;
#pragma unroll
    for (int kk = 0; kk < D; kk++) {
        float v = __shfl(x1, kk, 16);
        acc += v * W2s[kk * D + j];
    }
    hs2[((size_t)i << 4) + j] = f2fp8(acc * di);
}

// ---------- layer2 gather + BN2/ReLU ----------
__global__ __launch_bounds__(256) void k_gather2(const unsigned* __restrict__ rowptr,
                                                 const int* __restrict__ srcA,
                                                 const float* __restrict__ dis,
                                                 const unsigned char* __restrict__ hs2,
                                                 const float* __restrict__ b2,
                                                 const float* __restrict__ g2,
                                                 const float* __restrict__ be2,
                                                 const float* __restrict__ m2,
                                                 const float* __restrict__ v2,
                                                 f16* __restrict__ x2) {
    int tid = threadIdx.x;
    int i = blockIdx.x * 16 + (tid >> 4);
    int j = tid & 15;
    float self = fp82f(hs2[((size_t)i << 4) + j]);
    float sum = gather_row_sum(rowptr, srcA, hs2, i, j, self);
    float tt = dis[i] * sum + b2[j];
    tt = fmaxf(tt, 0.f);
    float sc = g2[j] * rsqrtf(v2[j] + BNEPS);
    x2[((size_t)i << 4) + j] = (f16)((tt - m2[j]) * sc + be2[j]);
}

// ---------- pooling ----------
__global__ __launch_bounds__(256) void k_pool(const f16* __restrict__ x2,
                                              const int* __restrict__ batch,
                                              unsigned* __restrict__ gmaxT,
                                              float* __restrict__ gsum,
                                              unsigned* __restrict__ gcnt) {
    __shared__ unsigned smax[32 * D];
    __shared__ float ssum[32 * D];
    __shared__ unsigned scnt[32];
    int tid = threadIdx.x;
    for (int s = tid; s < 32 * D; s += 256) { smax[s] = 0u; ssum[s] = 0.f; }
    if (tid < 32) scnt[tid] = 0u;
    __syncthreads();
    int n = blockIdx.x * 256 + tid;
    int g0 = batch[blockIdx.x * 256];
    if (n < N) {
        int lg = batch[n] - g0;
        const f16* xp = x2 + (size_t)n * D;
        if (lg < 32) {
            atomicAdd(&scnt[lg], 1u);
#pragma unroll
            for (int j = 0; j < D; j++) {
                float v = (float)xp[j];
                atomicMax(&smax[lg * D + j], f2ord(v));
                atomicAdd(&ssum[lg * D + j], v);
            }
        } else {
            int g = batch[n];
            atomicAdd(&gcnt[g], 1u);
#pragma unroll
            for (int j = 0; j < D; j++) {
                float v = (float)xp[j];
                atomicMax(&gmaxT[(size_t)g * D + j], f2ord(v));
                atomicAdd(&gsum[(size_t)g * D + j], v);
            }
        }
    }
    __syncthreads();
    for (int s = tid; s < 32 * D; s += 256) {
        int slot = s >> 4, j = s & 15;
        if (scnt[slot] > 0u) {
            int g = g0 + slot;
            atomicMax(&gmaxT[(size_t)g * D + j], smax[s]);
            atomicAdd(&gsum[(size_t)g * D + j], ssum[s]);
            if (j == 0) atomicAdd(&gcnt[g], scnt[slot]);
        }
    }
}

// ---------- head ----------
__global__ __launch_bounds__(256) void k_head(const unsigned* __restrict__ gmaxT,
                                              const float* __restrict__ gsum,
                                              const unsigned* __restrict__ gcnt,
                                              const float* __restrict__ Wb,
                                              const float* __restrict__ bb,
                                              const float* __restrict__ Wm,
                                              const float* __restrict__ bm,
                                              float* __restrict__ out) {
    __shared__ float Wbs[32 * 16];
    __shared__ float bbs[16], Wms[16];
    __shared__ float bm0;
    int tid = threadIdx.x;
    for (int i = tid; i < 32 * 16; i += 256) Wbs[i] = Wb[i];
    if (tid < 16) { bbs[tid] = bb[tid]; Wms[tid] = Wm[tid]; }
    if (tid == 0) bm0 = bm[0];
    __syncthreads();
    int g = blockIdx.x * 256 + tid;
    if (g >= G) return;
    float in[32];
    float inv = 1.0f / (float)gcnt[g];
#pragma unroll
    for (int j = 0; j < D; j++) {
        in[j] = ord2f(gmaxT[(size_t)g * D + j]);
        in[16 + j] = gsum[(size_t)g * D + j] * inv;
    }
    float z = bm0;
#pragma unroll
    for (int j = 0; j < 16; j++) {
        float acc = bbs[j];
#pragma unroll
        for (int k = 0; k < 32; k++) acc += in[k] * Wbs[k * 16 + j];
        acc = fmaxf(acc, 0.f);
        z += acc * Wms[j];
    }
    out[g] = 1.0f / (1.0f + expf(-z));
}

extern "C" void kernel_launch(void* const* d_in, const int* in_sizes, int n_in,
                              void* d_out, int out_size, void* d_ws, size_t ws_size,
                              hipStream_t stream) {
    const float* x   = (const float*)d_in[0];
    const int* ei    = (const int*)d_in[1];
    const int* rowp  = ei;
    const int* colp  = ei + E;
    const int* batch = (const int*)d_in[2];
    const float* W1  = (const float*)d_in[3];
    const float* b1  = (const float*)d_in[4];
    const float* g1  = (const float*)d_in[5];
    const float* be1 = (const float*)d_in[6];
    const float* m1  = (const float*)d_in[7];
    const float* v1  = (const float*)d_in[8];
    const float* W2  = (const float*)d_in[9];
    const float* b2  = (const float*)d_in[10];
    const float* g2  = (const float*)d_in[11];
    const float* be2 = (const float*)d_in[12];
    const float* m2  = (const float*)d_in[13];
    const float* v2  = (const float*)d_in[14];
    const float* Wb  = (const float*)d_in[15];
    const float* bb  = (const float*)d_in[16];
    const float* Wm  = (const float*)d_in[17];
    const float* bm  = (const float*)d_in[18];
    float* out = (float*)d_out;

    char* ws = (char*)d_ws;
    int*      srcA   = (int*)     (ws);                // E i32            [0, 25.6M)
    unsigned* tmp    = (unsigned*)(ws + 25600000);     // E u32 packed     [25.6M, 51.2M)
    unsigned char* hs1 = (unsigned char*)(ws + 25600000); // N*D fp8 (3.2MB) — overlays tmp AFTER k_bsort
    unsigned char* hs2 = (unsigned char*)(ws + 28800000); // N*D fp8 (3.2MB) — also in dead tmp area
    f16*      x2buf  = (f16*)     (ws + 32000000);     // N*D f16 (6.4MB)
    unsigned* rowptr = (unsigned*)(ws + 51200000);     // (N+1) u32
    float*    dis    = (float*)   (ws + 52000016);     // N f32
    unsigned* bucketCnt  = (unsigned*)(ws + 52800016);
    unsigned* bucketBase = (unsigned*)(ws + 52801600);
    unsigned* cursorB    = (unsigned*)(ws + 52803200);
    unsigned* gmaxT  = (unsigned*)(ws + 52804800);
    float*    gsum   = (float*)   (ws + 52870336);
    unsigned* gcnt   = (unsigned*)(ws + 52935872);

    const int NB = (N + 255) / 256;

    hipMemsetAsync(bucketCnt, 0, (NBKT + 1) * 4, stream);
    hipMemsetAsync(gmaxT, 0, (size_t)G * D * 4, stream);
    hipMemsetAsync(gsum, 0, (size_t)G * D * 4, stream);
    hipMemsetAsync(gcnt, 0, (size_t)G * 4, stream);

    k_hist<<<1024, 256, 0, stream>>>(colp, bucketCnt);
    k_bscan<<<1, 512, 0, stream>>>(bucketCnt, bucketBase, cursorB, rowptr);
    k_bin<<<BINB, 512, 0, stream>>>(rowp, colp, cursorB, tmp);
    k_bsort<<<NBKT, 512, 0, stream>>>(bucketBase, tmp, rowptr, dis, srcA);

    k_gemm1<<<512, 256, 0, stream>>>(x, W1, dis, hs1);

    k_gather1<<<N / 16, 256, 0, stream>>>(rowptr, srcA, dis, hs1,
                                          b1, g1, be1, m1, v1, W2, hs2);
    k_gather2<<<N / 16, 256, 0, stream>>>(rowptr, srcA, dis, hs2,
                                          b2, g2, be2, m2, v2, x2buf);

    k_pool<<<NB, 256, 0, stream>>>(x2buf, batch, gmaxT, gsum, gcnt);
    k_head<<<(G + 255) / 256, 256, 0, stream>>>(gmaxT, gsum, gcnt, Wb, bb, Wm, bm, out);
}

// Round 5
// 458.525 us; speedup vs baseline: 1.2110x; 1.0118x over previous
//
#include <hip/hip_runtime.h>
#include <math.h>

#define N   200000
#define E   6400000
#define IN_ 128
#define D   16
#define G   1024
#define BNEPS 1e-5f

#define BSH   9                      // 512 cols per bucket
#define NBKT  391                    // ceil(N / 512)
#define CH    8192                   // edges per k_bin block
#define BINB  782                    // ceil(E / CH)
#define BCAP  18432                  // LDS staging capacity for one bucket (72 KB)

typedef _Float16 f16;
typedef __attribute__((ext_vector_type(8))) _Float16 f16x8;
typedef __attribute__((ext_vector_type(4))) float f32x4;
typedef __attribute__((ext_vector_type(2))) float f32x2;

// ---------- helpers ----------
__device__ __forceinline__ unsigned f2ord(float f) {
    unsigned b = __float_as_uint(f);
    return (b & 0x80000000u) ? ~b : (b | 0x80000000u);
}
__device__ __forceinline__ float ord2f(unsigned u) {
    return __uint_as_float((u & 0x80000000u) ? (u & 0x7FFFFFFFu) : ~u);
}
// f32 -> fp8 e4m3 (OCP on gfx950), single byte
__device__ __forceinline__ unsigned char f2fp8(float v) {
    return (unsigned char)(__builtin_amdgcn_cvt_pk_fp8_f32(v, v, 0, false) & 0xFF);
}
__device__ __forceinline__ float fp82f(unsigned char b) {
    return __builtin_amdgcn_cvt_f32_fp8((unsigned)b, 0);
}

// ---------- bucket histogram ----------
__global__ __launch_bounds__(256) void k_hist(const int* __restrict__ col,
                                              unsigned* __restrict__ bucketCnt) {
    __shared__ unsigned h[NBKT];
    for (int i = threadIdx.x; i < NBKT; i += 256) h[i] = 0u;
    __syncthreads();
    int stride = gridDim.x * 256;
    for (int e = blockIdx.x * 256 + threadIdx.x; e < E; e += stride)
        atomicAdd(&h[col[e] >> BSH], 1u);
    __syncthreads();
    for (int i = threadIdx.x; i < NBKT; i += 256)
        if (h[i]) atomicAdd(&bucketCnt[i], h[i]);
}

// ---------- scan bucket counts ----------
__global__ __launch_bounds__(512) void k_bscan(const unsigned* __restrict__ bucketCnt,
                                               unsigned* __restrict__ bucketBase,
                                               unsigned* __restrict__ cursorB,
                                               unsigned* __restrict__ rowptr) {
    __shared__ unsigned s[512];
    int t = threadIdx.x;
    s[t] = (t < NBKT) ? bucketCnt[t] : 0u;
    __syncthreads();
    for (int off = 1; off < 512; off <<= 1) {
        unsigned v = (t >= off) ? s[t - off] : 0u;
        __syncthreads();
        s[t] += v;
        __syncthreads();
    }
    unsigned excl = (t > 0) ? s[t - 1] : 0u;
    if (t <= NBKT) {
        bucketBase[t] = excl;
        cursorB[t] = excl;
    }
    if (t == 0) rowptr[N] = E;
}

// ---------- phase 1: bin edges by bucket ----------
__global__ __launch_bounds__(512) void k_bin(const int* __restrict__ row,
                                             const int* __restrict__ col,
                                             unsigned* __restrict__ cursorB,
                                             unsigned* __restrict__ tmp) {
    __shared__ unsigned hist[512];   // after scan phase: lbase
    __shared__ unsigned offs[512];   // inclusive scan (lbase[b+1])
    __shared__ unsigned lcur[512];
    __shared__ unsigned gbase[512];
    __shared__ unsigned sbuf[CH];    // 32 KB
    int tid = threadIdx.x;
    int base = blockIdx.x * CH;
    int cnt = min(CH, E - base);
    hist[tid] = 0u;
    __syncthreads();
    for (int i = tid; i < cnt; i += 512)
        atomicAdd(&hist[col[base + i] >> BSH], 1u);
    __syncthreads();
    offs[tid] = hist[tid];
    __syncthreads();
    for (int off = 1; off < 512; off <<= 1) {
        unsigned v = (tid >= off) ? offs[tid - off] : 0u;
        __syncthreads();
        offs[tid] += v;
        __syncthreads();
    }
    unsigned lb = (tid > 0) ? offs[tid - 1] : 0u;
    unsigned c0 = offs[tid] - lb;
    lcur[tid] = lb;
    hist[tid] = lb;   // hist now holds lbase
    if (tid < NBKT && c0) gbase[tid] = atomicAdd(&cursorB[tid], c0);
    __syncthreads();
    for (int i = tid; i < cnt; i += 512) {
        int c = col[base + i];
        int r = row[base + i];
        int b = c >> BSH;
        unsigned p = atomicAdd(&lcur[b], 1u);
        sbuf[p] = (unsigned)r | ((unsigned)(c & ((1 << BSH) - 1)) << 18);
    }
    __syncthreads();
    // bucket-major coalesced copy-out: one wave per bucket
    int wv = tid >> 6, ln = tid & 63;
    for (int b = wv; b < NBKT; b += 8) {
        unsigned l0 = hist[b], l1 = offs[b], gb = gbase[b];
        for (unsigned i2 = l0 + ln; i2 < l1; i2 += 64)
            tmp[gb + (i2 - l0)] = sbuf[i2];
    }
}

// ---------- phase 2: per-bucket counting sort (LDS-staged coalesced output) ----------
__global__ __launch_bounds__(512) void k_bsort(const unsigned* __restrict__ bucketBase,
                                               const unsigned* __restrict__ tmp,
                                               unsigned* __restrict__ rowptr,
                                               float* __restrict__ dis,
                                               int* __restrict__ srcA) {
    __shared__ unsigned cnt[512];
    __shared__ unsigned offs[512];
    __shared__ unsigned lcur[512];
    __shared__ unsigned sout[BCAP];  // 72 KB staging: scatter here, stream out coalesced
    int tid = threadIdx.x;
    int b = blockIdx.x;
    unsigned s0 = bucketBase[b], s1 = bucketBase[b + 1];
    cnt[tid] = 0u;
    __syncthreads();
    for (unsigned i = s0 + tid; i < s1; i += 512)
        atomicAdd(&cnt[tmp[i] >> 18], 1u);
    __syncthreads();
    offs[tid] = cnt[tid];
    __syncthreads();
    for (int off = 1; off < 512; off <<= 1) {
        unsigned v = (tid >= off) ? offs[tid - off] : 0u;
        __syncthreads();
        offs[tid] += v;
        __syncthreads();
    }
    unsigned excl = (tid > 0) ? offs[tid - 1] : 0u;
    int c = (b << BSH) + tid;
    if (c < N) {
        rowptr[c] = s0 + excl;
        dis[c] = rsqrtf((float)cnt[tid] + 1.0f);
    }
    unsigned cap = s1 - s0;
    if (cap <= (unsigned)BCAP) {
        lcur[tid] = excl;                       // bucket-local offsets
        __syncthreads();
        for (unsigned i = s0 + tid; i < s1; i += 512) {
            unsigned p = tmp[i];
            unsigned pos = atomicAdd(&lcur[p >> 18], 1u);
            sout[pos] = p & 0x3FFFFu;
        }
        __syncthreads();
        // coalesced contiguous copy-out
        for (unsigned i = tid; i < cap; i += 512)
            srcA[s0 + i] = (int)sout[i];
    } else {
        // statistically-unreachable fallback: direct global scatter
        lcur[tid] = s0 + excl;
        __syncthreads();
        for (unsigned i = s0 + tid; i < s1; i += 512) {
            unsigned p = tmp[i];
            unsigned pos = atomicAdd(&lcur[p >> 18], 1u);
            srcA[pos] = (int)(p & 0x3FFFFu);
        }
    }
}

// ---------- hs1 = fp8((x @ W1) * dis) via MFMA 16x16x32 f16 ----------
__global__ __launch_bounds__(256) void k_gemm1(const float* __restrict__ x,
                                               const float* __restrict__ W1,
                                               const float* __restrict__ dis,
                                               unsigned char* __restrict__ hs) {
    __shared__ f16 Wh[IN_ * D];
    int tid = threadIdx.x;
    for (int i = tid; i < IN_ * D; i += 256) Wh[i] = (f16)W1[i];
    __syncthreads();
    int lane = tid & 63;
    int wave = tid >> 6;
    int m = lane & 15, quad = lane >> 4;
    f16x8 bfrag[4];
#pragma unroll
    for (int s = 0; s < 4; s++)
#pragma unroll
        for (int jj = 0; jj < 8; jj++)
            bfrag[s][jj] = Wh[(s * 32 + quad * 8 + jj) * D + m];
    int gwave = blockIdx.x * 4 + wave;
    int nwaves = gridDim.x * 4;
    const int ntiles = N / 16;
    for (int t = gwave; t < ntiles; t += nwaves) {
        int n0 = t * 16;
        const float* xrow = x + (size_t)(n0 + m) * IN_ + quad * 8;
        f32x4 acc = {0.f, 0.f, 0.f, 0.f};
#pragma unroll
        for (int s = 0; s < 4; s++) {
            float4 lo = *(const float4*)(xrow + s * 32);
            float4 hi = *(const float4*)(xrow + s * 32 + 4);
            f16x8 a;
            a[0] = (f16)lo.x; a[1] = (f16)lo.y; a[2] = (f16)lo.z; a[3] = (f16)lo.w;
            a[4] = (f16)hi.x; a[5] = (f16)hi.y; a[6] = (f16)hi.z; a[7] = (f16)hi.w;
            acc = __builtin_amdgcn_mfma_f32_16x16x32_f16(a, bfrag[s], acc, 0, 0, 0);
        }
#pragma unroll
        for (int r = 0; r < 4; r++) {
            int rowi = n0 + quad * 4 + r;
            hs[(size_t)rowi * D + m] = f2fp8(acc[r] * dis[rowi]);
        }
    }
}

// ---------- wide gather core (fp8 table, full-row-per-lane, 2-deep MLP) ----------
// 16 lanes per node. Each lane owns edge slots j and j+16: one iteration covers
// 32 edges with TWO independent predicated uint4 gathers in flight per lane
// (doubles outstanding transactions vs 16-edge version). srcA for the next
// iteration is prefetched so its latency hides under the current gathers.
// Remainder handled by predication. Epilogue butterfly: lane j = feature j.
__device__ __forceinline__ float gather_row_sum(const unsigned* __restrict__ rowptr,
                                                const int* __restrict__ srcA,
                                                const unsigned char* __restrict__ hs,
                                                int i, int j, float seed) {
    unsigned start = rowptr[i], end = rowptr[i + 1];
    float acc[16];
#pragma unroll
    for (int k = 0; k < 16; k++) acc[k] = 0.f;
    bool val0 = (start + (unsigned)j) < end;
    bool val1 = (start + 16u + (unsigned)j) < end;
    int src0 = 0, src1 = 0;
    if (val0) src0 = __builtin_nontemporal_load(&srcA[start + j]);
    if (val1) src1 = __builtin_nontemporal_load(&srcA[start + 16 + j]);
    for (unsigned base = start; base < end; base += 32) {
        bool nval0 = (base + 32u + (unsigned)j) < end;
        bool nval1 = (base + 48u + (unsigned)j) < end;
        int nsrc0 = 0, nsrc1 = 0;
        if (nval0) nsrc0 = __builtin_nontemporal_load(&srcA[base + 32 + j]);
        if (nval1) nsrc1 = __builtin_nontemporal_load(&srcA[base + 48 + j]);
        uint4 v0, v1;
        if (val0) v0 = *(const uint4*)(hs + ((size_t)src0 << 4));
        if (val1) v1 = *(const uint4*)(hs + ((size_t)src1 << 4));
        if (val0) {
            f32x2 f;
            f = __builtin_amdgcn_cvt_pk_f32_fp8(v0.x, false); acc[0] += f.x;  acc[1] += f.y;
            f = __builtin_amdgcn_cvt_pk_f32_fp8(v0.x, true);  acc[2] += f.x;  acc[3] += f.y;
            f = __builtin_amdgcn_cvt_pk_f32_fp8(v0.y, false); acc[4] += f.x;  acc[5] += f.y;
            f = __builtin_amdgcn_cvt_pk_f32_fp8(v0.y, true);  acc[6] += f.x;  acc[7] += f.y;
            f = __builtin_amdgcn_cvt_pk_f32_fp8(v0.z, false); acc[8] += f.x;  acc[9] += f.y;
            f = __builtin_amdgcn_cvt_pk_f32_fp8(v0.z, true);  acc[10] += f.x; acc[11] += f.y;
            f = __builtin_amdgcn_cvt_pk_f32_fp8(v0.w, false); acc[12] += f.x; acc[13] += f.y;
            f = __builtin_amdgcn_cvt_pk_f32_fp8(v0.w, true);  acc[14] += f.x; acc[15] += f.y;
        }
        if (val1) {
            f32x2 f;
            f = __builtin_amdgcn_cvt_pk_f32_fp8(v1.x, false); acc[0] += f.x;  acc[1] += f.y;
            f = __builtin_amdgcn_cvt_pk_f32_fp8(v1.x, true);  acc[2] += f.x;  acc[3] += f.y;
            f = __builtin_amdgcn_cvt_pk_f32_fp8(v1.y, false); acc[4] += f.x;  acc[5] += f.y;
            f = __builtin_amdgcn_cvt_pk_f32_fp8(v1.y, true);  acc[6] += f.x;  acc[7] += f.y;
            f = __builtin_amdgcn_cvt_pk_f32_fp8(v1.z, false); acc[8] += f.x;  acc[9] += f.y;
            f = __builtin_amdgcn_cvt_pk_f32_fp8(v1.z, true);  acc[10] += f.x; acc[11] += f.y;
            f = __builtin_amdgcn_cvt_pk_f32_fp8(v1.w, false); acc[12] += f.x; acc[13] += f.y;
            f = __builtin_amdgcn_cvt_pk_f32_fp8(v1.w, true);  acc[14] += f.x; acc[15] += f.y;
        }
        val0 = nval0; src0 = nsrc0;
        val1 = nval1; src1 = nsrc1;
    }
    // reduce-and-split butterfly: 15 shfl + 15 add, static reg indices only
    float r8[8];
#pragma unroll
    for (int k = 0; k < 8; k++) {
        float keep = (j & 8) ? acc[k + 8] : acc[k];
        float give = (j & 8) ? acc[k] : acc[k + 8];
        r8[k] = keep + __shfl_xor(give, 8, 16);
    }
    float r4[4];
#pragma unroll
    for (int k = 0; k < 4; k++) {
        float keep = (j & 4) ? r8[k + 4] : r8[k];
        float give = (j & 4) ? r8[k] : r8[k + 4];
        r4[k] = keep + __shfl_xor(give, 4, 16);
    }
    float r2[2];
#pragma unroll
    for (int k = 0; k < 2; k++) {
        float keep = (j & 2) ? r4[k + 2] : r4[k];
        float give = (j & 2) ? r4[k] : r4[k + 2];
        r2[k] = keep + __shfl_xor(give, 2, 16);
    }
    float keep = (j & 1) ? r2[1] : r2[0];
    float give = (j & 1) ? r2[0] : r2[1];
    float x = keep + __shfl_xor(give, 1, 16);
    return x + seed;
}

// ---------- layer1 gather + BN1/ReLU + GEMM2 ----------
__global__ __launch_bounds__(256) void k_gather1(const unsigned* __restrict__ rowptr,
                                                 const int* __restrict__ srcA,
                                                 const float* __restrict__ dis,
                                                 const unsigned char* __restrict__ hs1,
                                                 const float* __restrict__ b1,
                                                 const float* __restrict__ g1,
                                                 const float* __restrict__ be1,
                                                 const float* __restrict__ m1,
                                                 const float* __restrict__ v1,
                                                 const float* __restrict__ W2,
                                                 unsigned char* __restrict__ hs2) {
    __shared__ float W2s[D * D];
    int tid = threadIdx.x;
    if (tid < D * D) W2s[tid] = W2[tid];
    __syncthreads();
    int i = blockIdx.x * 16 + (tid >> 4);
    int j = tid & 15;
    float self = fp82f(hs1[((size_t)i << 4) + j]);
    float sum = gather_row_sum(rowptr, srcA, hs1, i, j, self);
    float di = dis[i];
    float tt = di * sum + b1[j];
    tt = fmaxf(tt, 0.f);
    float sc = g1[j] * rsqrtf(v1[j] + BNEPS);
    float x1 = (tt - m1[j]) * sc + be1[j];
    float acc = 0.f;
#pragma unroll
    for (int kk = 0; kk < D; kk++) {
        float v = __shfl(x1, kk, 16);
        acc += v * W2s[kk * D + j];
    }
    hs2[((size_t)i << 4) + j] = f2fp8(acc * di);
}

// ---------- layer2 gather + BN2/ReLU ----------
__global__ __launch_bounds__(256) void k_gather2(const unsigned* __restrict__ rowptr,
                                                 const int* __restrict__ srcA,
                                                 const float* __restrict__ dis,
                                                 const unsigned char* __restrict__ hs2,
                                                 const float* __restrict__ b2,
                                                 const float* __restrict__ g2,
                                                 const float* __restrict__ be2,
                                                 const float* __restrict__ m2,
                                                 const float* __restrict__ v2,
                                                 f16* __restrict__ x2) {
    int tid = threadIdx.x;
    int i = blockIdx.x * 16 + (tid >> 4);
    int j = tid & 15;
    float self = fp82f(hs2[((size_t)i << 4) + j]);
    float sum = gather_row_sum(rowptr, srcA, hs2, i, j, self);
    float tt = dis[i] * sum + b2[j];
    tt = fmaxf(tt, 0.f);
    float sc = g2[j] * rsqrtf(v2[j] + BNEPS);
    x2[((size_t)i << 4) + j] = (f16)((tt - m2[j]) * sc + be2[j]);
}

// ---------- pooling ----------
__global__ __launch_bounds__(256) void k_pool(const f16* __restrict__ x2,
                                              const int* __restrict__ batch,
                                              unsigned* __restrict__ gmaxT,
                                              float* __restrict__ gsum,
                                              unsigned* __restrict__ gcnt) {
    __shared__ unsigned smax[32 * D];
    __shared__ float ssum[32 * D];
    __shared__ unsigned scnt[32];
    int tid = threadIdx.x;
    for (int s = tid; s < 32 * D; s += 256) { smax[s] = 0u; ssum[s] = 0.f; }
    if (tid < 32) scnt[tid] = 0u;
    __syncthreads();
    int n = blockIdx.x * 256 + tid;
    int g0 = batch[blockIdx.x * 256];
    if (n < N) {
        int lg = batch[n] - g0;
        const f16* xp = x2 + (size_t)n * D;
        if (lg < 32) {
            atomicAdd(&scnt[lg], 1u);
#pragma unroll
            for (int j = 0; j < D; j++) {
                float v = (float)xp[j];
                atomicMax(&smax[lg * D + j], f2ord(v));
                atomicAdd(&ssum[lg * D + j], v);
            }
        } else {
            int g = batch[n];
            atomicAdd(&gcnt[g], 1u);
#pragma unroll
            for (int j = 0; j < D; j++) {
                float v = (float)xp[j];
                atomicMax(&gmaxT[(size_t)g * D + j], f2ord(v));
                atomicAdd(&gsum[(size_t)g * D + j], v);
            }
        }
    }
    __syncthreads();
    for (int s = tid; s < 32 * D; s += 256) {
        int slot = s >> 4, j = s & 15;
        if (scnt[slot] > 0u) {
            int g = g0 + slot;
            atomicMax(&gmaxT[(size_t)g * D + j], smax[s]);
            atomicAdd(&gsum[(size_t)g * D + j], ssum[s]);
            if (j == 0) atomicAdd(&gcnt[g], scnt[slot]);
        }
    }
}

// ---------- head ----------
__global__ __launch_bounds__(256) void k_head(const unsigned* __restrict__ gmaxT,
                                              const float* __restrict__ gsum,
                                              const unsigned* __restrict__ gcnt,
                                              const float* __restrict__ Wb,
                                              const float* __restrict__ bb,
                                              const float* __restrict__ Wm,
                                              const float* __restrict__ bm,
                                              float* __restrict__ out) {
    __shared__ float Wbs[32 * 16];
    __shared__ float bbs[16], Wms[16];
    __shared__ float bm0;
    int tid = threadIdx.x;
    for (int i = tid; i < 32 * 16; i += 256) Wbs[i] = Wb[i];
    if (tid < 16) { bbs[tid] = bb[tid]; Wms[tid] = Wm[tid]; }
    if (tid == 0) bm0 = bm[0];
    __syncthreads();
    int g = blockIdx.x * 256 + tid;
    if (g >= G) return;
    float in[32];
    float inv = 1.0f / (float)gcnt[g];
#pragma unroll
    for (int j = 0; j < D; j++) {
        in[j] = ord2f(gmaxT[(size_t)g * D + j]);
        in[16 + j] = gsum[(size_t)g * D + j] * inv;
    }
    float z = bm0;
#pragma unroll
    for (int j = 0; j < 16; j++) {
        float acc = bbs[j];
#pragma unroll
        for (int k = 0; k < 32; k++) acc += in[k] * Wbs[k * 16 + j];
        acc = fmaxf(acc, 0.f);
        z += acc * Wms[j];
    }
    out[g] = 1.0f / (1.0f + expf(-z));
}

extern "C" void kernel_launch(void* const* d_in, const int* in_sizes, int n_in,
                              void* d_out, int out_size, void* d_ws, size_t ws_size,
                              hipStream_t stream) {
    const float* x   = (const float*)d_in[0];
    const int* ei    = (const int*)d_in[1];
    const int* rowp  = ei;
    const int* colp  = ei + E;
    const int* batch = (const int*)d_in[2];
    const float* W1  = (const float*)d_in[3];
    const float* b1  = (const float*)d_in[4];
    const float* g1  = (const float*)d_in[5];
    const float* be1 = (const float*)d_in[6];
    const float* m1  = (const float*)d_in[7];
    const float* v1  = (const float*)d_in[8];
    const float* W2  = (const float*)d_in[9];
    const float* b2  = (const float*)d_in[10];
    const float* g2  = (const float*)d_in[11];
    const float* be2 = (const float*)d_in[12];
    const float* m2  = (const float*)d_in[13];
    const float* v2  = (const float*)d_in[14];
    const float* Wb  = (const float*)d_in[15];
    const float* bb  = (const float*)d_in[16];
    const float* Wm  = (const float*)d_in[17];
    const float* bm  = (const float*)d_in[18];
    float* out = (float*)d_out;

    char* ws = (char*)d_ws;
    int*      srcA   = (int*)     (ws);                // E i32            [0, 25.6M)
    unsigned* tmp    = (unsigned*)(ws + 25600000);     // E u32 packed     [25.6M, 51.2M)
    unsigned char* hs1 = (unsigned char*)(ws + 25600000); // N*D fp8 (3.2MB) — overlays tmp AFTER k_bsort
    unsigned char* hs2 = (unsigned char*)(ws + 28800000); // N*D fp8 (3.2MB) — also in dead tmp area
    f16*      x2buf  = (f16*)     (ws + 32000000);     // N*D f16 (6.4MB)
    unsigned* rowptr = (unsigned*)(ws + 51200000);     // (N+1) u32
    float*    dis    = (float*)   (ws + 52000016);     // N f32
    unsigned* bucketCnt  = (unsigned*)(ws + 52800016);
    unsigned* bucketBase = (unsigned*)(ws + 52801600);
    unsigned* cursorB    = (unsigned*)(ws + 52803200);
    unsigned* gmaxT  = (unsigned*)(ws + 52804800);
    float*    gsum   = (float*)   (ws + 52870336);
    unsigned* gcnt   = (unsigned*)(ws + 52935872);

    const int NB = (N + 255) / 256;

    hipMemsetAsync(bucketCnt, 0, (NBKT + 1) * 4, stream);
    hipMemsetAsync(gmaxT, 0, (size_t)G * D * 4, stream);
    hipMemsetAsync(gsum, 0, (size_t)G * D * 4, stream);
    hipMemsetAsync(gcnt, 0, (size_t)G * 4, stream);

    k_hist<<<1024, 256, 0, stream>>>(colp, bucketCnt);
    k_bscan<<<1, 512, 0, stream>>>(bucketCnt, bucketBase, cursorB, rowptr);
    k_bin<<<BINB, 512, 0, stream>>>(rowp, colp, cursorB, tmp);
    k_bsort<<<NBKT, 512, 0, stream>>>(bucketBase, tmp, rowptr, dis, srcA);

    k_gemm1<<<512, 256, 0, stream>>>(x, W1, dis, hs1);

    k_gather1<<<N / 16, 256, 0, stream>>>(rowptr, srcA, dis, hs1,
                                          b1, g1, be1, m1, v1, W2, hs2);
    k_gather2<<<N / 16, 256, 0, stream>>>(rowptr, srcA, dis, hs2,
                                          b2, g2, be2, m2, v2, x2buf);

    k_pool<<<NB, 256, 0, stream>>>(x2buf, batch, gmaxT, gsum, gcnt);
    k_head<<<(G + 255) / 256, 256, 0, stream>>>(gmaxT, gsum, gcnt, Wb, bb, Wm, bm, out);
}

// Round 6
// 426.794 us; speedup vs baseline: 1.3010x; 1.0743x over previous
//
#include <hip/hip_runtime.h>
#include <math.h>

#define N   200000
#define E   6400000
#define IN_ 128
#define D   16
#define G   1024
#define BNEPS 1e-5f

#define BSH   9                      // 512 cols per bucket
#define NBKT  391                    // ceil(N / 512)
#define CH    8192                   // edges per k_bin block
#define BINB  782                    // ceil(E / CH)
#define BCAP  18432                  // LDS staging capacity for one bucket (72 KB)

typedef _Float16 f16;
typedef __attribute__((ext_vector_type(8))) _Float16 f16x8;
typedef __attribute__((ext_vector_type(4))) float f32x4;
typedef __attribute__((ext_vector_type(2))) float f32x2;

// ---------- helpers ----------
__device__ __forceinline__ unsigned f2ord(float f) {
    unsigned b = __float_as_uint(f);
    return (b & 0x80000000u) ? ~b : (b | 0x80000000u);
}
__device__ __forceinline__ float ord2f(unsigned u) {
    return __uint_as_float((u & 0x80000000u) ? (u & 0x7FFFFFFFu) : ~u);
}
// f32 -> fp8 e4m3 (OCP on gfx950), single byte
__device__ __forceinline__ unsigned char f2fp8(float v) {
    return (unsigned char)(__builtin_amdgcn_cvt_pk_fp8_f32(v, v, 0, false) & 0xFF);
}
__device__ __forceinline__ float fp82f(unsigned char b) {
    return __builtin_amdgcn_cvt_f32_fp8((unsigned)b, 0);
}

// ---------- bucket histogram ----------
__global__ __launch_bounds__(256) void k_hist(const int* __restrict__ col,
                                              unsigned* __restrict__ bucketCnt) {
    __shared__ unsigned h[NBKT];
    for (int i = threadIdx.x; i < NBKT; i += 256) h[i] = 0u;
    __syncthreads();
    int stride = gridDim.x * 256;
    for (int e = blockIdx.x * 256 + threadIdx.x; e < E; e += stride)
        atomicAdd(&h[col[e] >> BSH], 1u);
    __syncthreads();
    for (int i = threadIdx.x; i < NBKT; i += 256)
        if (h[i]) atomicAdd(&bucketCnt[i], h[i]);
}

// ---------- scan bucket counts ----------
__global__ __launch_bounds__(512) void k_bscan(const unsigned* __restrict__ bucketCnt,
                                               unsigned* __restrict__ bucketBase,
                                               unsigned* __restrict__ cursorB,
                                               unsigned* __restrict__ rowptr) {
    __shared__ unsigned s[512];
    int t = threadIdx.x;
    s[t] = (t < NBKT) ? bucketCnt[t] : 0u;
    __syncthreads();
    for (int off = 1; off < 512; off <<= 1) {
        unsigned v = (t >= off) ? s[t - off] : 0u;
        __syncthreads();
        s[t] += v;
        __syncthreads();
    }
    unsigned excl = (t > 0) ? s[t - 1] : 0u;
    if (t <= NBKT) {
        bucketBase[t] = excl;
        cursorB[t] = excl;
    }
    if (t == 0) rowptr[N] = E;
}

// ---------- phase 1: bin edges by bucket ----------
__global__ __launch_bounds__(512) void k_bin(const int* __restrict__ row,
                                             const int* __restrict__ col,
                                             unsigned* __restrict__ cursorB,
                                             unsigned* __restrict__ tmp) {
    __shared__ unsigned hist[512];   // after scan phase: lbase
    __shared__ unsigned offs[512];   // inclusive scan (lbase[b+1])
    __shared__ unsigned lcur[512];
    __shared__ unsigned gbase[512];
    __shared__ unsigned sbuf[CH];    // 32 KB
    int tid = threadIdx.x;
    int base = blockIdx.x * CH;
    int cnt = min(CH, E - base);
    hist[tid] = 0u;
    __syncthreads();
    for (int i = tid; i < cnt; i += 512)
        atomicAdd(&hist[col[base + i] >> BSH], 1u);
    __syncthreads();
    offs[tid] = hist[tid];
    __syncthreads();
    for (int off = 1; off < 512; off <<= 1) {
        unsigned v = (tid >= off) ? offs[tid - off] : 0u;
        __syncthreads();
        offs[tid] += v;
        __syncthreads();
    }
    unsigned lb = (tid > 0) ? offs[tid - 1] : 0u;
    unsigned c0 = offs[tid] - lb;
    lcur[tid] = lb;
    hist[tid] = lb;   // hist now holds lbase
    if (tid < NBKT && c0) gbase[tid] = atomicAdd(&cursorB[tid], c0);
    __syncthreads();
    for (int i = tid; i < cnt; i += 512) {
        int c = col[base + i];
        int r = row[base + i];
        int b = c >> BSH;
        unsigned p = atomicAdd(&lcur[b], 1u);
        sbuf[p] = (unsigned)r | ((unsigned)(c & ((1 << BSH) - 1)) << 18);
    }
    __syncthreads();
    // bucket-major coalesced copy-out: one wave per bucket
    int wv = tid >> 6, ln = tid & 63;
    for (int b = wv; b < NBKT; b += 8) {
        unsigned l0 = hist[b], l1 = offs[b], gb = gbase[b];
        for (unsigned i2 = l0 + ln; i2 < l1; i2 += 64)
            tmp[gb + (i2 - l0)] = sbuf[i2];
    }
}

// ---------- phase 2: per-bucket counting sort (LDS-staged coalesced output) ----------
__global__ __launch_bounds__(512) void k_bsort(const unsigned* __restrict__ bucketBase,
                                               const unsigned* __restrict__ tmp,
                                               unsigned* __restrict__ rowptr,
                                               float* __restrict__ dis,
                                               int* __restrict__ srcA) {
    __shared__ unsigned cnt[512];
    __shared__ unsigned offs[512];
    __shared__ unsigned lcur[512];
    __shared__ unsigned sout[BCAP];  // 72 KB staging: scatter here, stream out coalesced
    int tid = threadIdx.x;
    int b = blockIdx.x;
    unsigned s0 = bucketBase[b], s1 = bucketBase[b + 1];
    cnt[tid] = 0u;
    __syncthreads();
    for (unsigned i = s0 + tid; i < s1; i += 512)
        atomicAdd(&cnt[tmp[i] >> 18], 1u);
    __syncthreads();
    offs[tid] = cnt[tid];
    __syncthreads();
    for (int off = 1; off < 512; off <<= 1) {
        unsigned v = (tid >= off) ? offs[tid - off] : 0u;
        __syncthreads();
        offs[tid] += v;
        __syncthreads();
    }
    unsigned excl = (tid > 0) ? offs[tid - 1] : 0u;
    int c = (b << BSH) + tid;
    if (c < N) {
        rowptr[c] = s0 + excl;
        dis[c] = rsqrtf((float)cnt[tid] + 1.0f);
    }
    unsigned cap = s1 - s0;
    if (cap <= (unsigned)BCAP) {
        lcur[tid] = excl;                       // bucket-local offsets
        __syncthreads();
        for (unsigned i = s0 + tid; i < s1; i += 512) {
            unsigned p = tmp[i];
            unsigned pos = atomicAdd(&lcur[p >> 18], 1u);
            sout[pos] = p & 0x3FFFFu;
        }
        __syncthreads();
        // coalesced contiguous copy-out
        for (unsigned i = tid; i < cap; i += 512)
            srcA[s0 + i] = (int)sout[i];
    } else {
        // statistically-unreachable fallback: direct global scatter
        lcur[tid] = s0 + excl;
        __syncthreads();
        for (unsigned i = s0 + tid; i < s1; i += 512) {
            unsigned p = tmp[i];
            unsigned pos = atomicAdd(&lcur[p >> 18], 1u);
            srcA[pos] = (int)(p & 0x3FFFFu);
        }
    }
}

// ---------- hs1 = fp8((x @ W1) * dis) via MFMA 16x16x32 f16 ----------
__global__ __launch_bounds__(256) void k_gemm1(const float* __restrict__ x,
                                               const float* __restrict__ W1,
                                               const float* __restrict__ dis,
                                               unsigned char* __restrict__ hs) {
    __shared__ f16 Wh[IN_ * D];
    int tid = threadIdx.x;
    for (int i = tid; i < IN_ * D; i += 256) Wh[i] = (f16)W1[i];
    __syncthreads();
    int lane = tid & 63;
    int wave = tid >> 6;
    int m = lane & 15, quad = lane >> 4;
    f16x8 bfrag[4];
#pragma unroll
    for (int s = 0; s < 4; s++)
#pragma unroll
        for (int jj = 0; jj < 8; jj++)
            bfrag[s][jj] = Wh[(s * 32 + quad * 8 + jj) * D + m];
    int gwave = blockIdx.x * 4 + wave;
    int nwaves = gridDim.x * 4;
    const int ntiles = N / 16;
    for (int t = gwave; t < ntiles; t += nwaves) {
        int n0 = t * 16;
        const float* xrow = x + (size_t)(n0 + m) * IN_ + quad * 8;
        f32x4 acc = {0.f, 0.f, 0.f, 0.f};
#pragma unroll
        for (int s = 0; s < 4; s++) {
            float4 lo = *(const float4*)(xrow + s * 32);
            float4 hi = *(const float4*)(xrow + s * 32 + 4);
            f16x8 a;
            a[0] = (f16)lo.x; a[1] = (f16)lo.y; a[2] = (f16)lo.z; a[3] = (f16)lo.w;
            a[4] = (f16)hi.x; a[5] = (f16)hi.y; a[6] = (f16)hi.z; a[7] = (f16)hi.w;
            acc = __builtin_amdgcn_mfma_f32_16x16x32_f16(a, bfrag[s], acc, 0, 0, 0);
        }
#pragma unroll
        for (int r = 0; r < 4; r++) {
            int rowi = n0 + quad * 4 + r;
            hs[(size_t)rowi * D + m] = f2fp8(acc[r] * dis[rowi]);
        }
    }
}

#define ACC8(q)                                                                           \
    {                                                                                     \
        f32x2 f;                                                                          \
        f = __builtin_amdgcn_cvt_pk_f32_fp8((q).x, false); acc[0] += f.x;  acc[1] += f.y; \
        f = __builtin_amdgcn_cvt_pk_f32_fp8((q).x, true);  acc[2] += f.x;  acc[3] += f.y; \
        f = __builtin_amdgcn_cvt_pk_f32_fp8((q).y, false); acc[4] += f.x;  acc[5] += f.y; \
        f = __builtin_amdgcn_cvt_pk_f32_fp8((q).y, true);  acc[6] += f.x;  acc[7] += f.y; \
        f = __builtin_amdgcn_cvt_pk_f32_fp8((q).z, false); acc[8] += f.x;  acc[9] += f.y; \
        f = __builtin_amdgcn_cvt_pk_f32_fp8((q).z, true);  acc[10] += f.x; acc[11] += f.y;\
        f = __builtin_amdgcn_cvt_pk_f32_fp8((q).w, false); acc[12] += f.x; acc[13] += f.y;\
        f = __builtin_amdgcn_cvt_pk_f32_fp8((q).w, true);  acc[14] += f.x; acc[15] += f.y;\
    }

// ---------- wide gather core (fp8 table, full-row-per-lane, 64 edges/iter) ----------
// 16 lanes per node. Each lane owns 4 edge slots (j, j+16, j+32, j+48): one
// iteration covers 64 edges with FOUR independent predicated uint4 gathers in
// flight per lane. Average degree ~33 => the loop is a single straight-line
// iteration for ~95% of nodes (no loop-carried dependency). srcA slot loads are
// 4 fully-coalesced 64B lines. Epilogue butterfly: lane j = feature j.
__device__ __forceinline__ float gather_row_sum(const unsigned* __restrict__ rowptr,
                                                const int* __restrict__ srcA,
                                                const unsigned char* __restrict__ hs,
                                                int i, int j, float seed) {
    unsigned start = rowptr[i], end = rowptr[i + 1];
    float acc[16];
#pragma unroll
    for (int k = 0; k < 16; k++) acc[k] = 0.f;
    for (unsigned base = start; base < end; base += 64) {
        unsigned e0 = base + (unsigned)j;
        bool v0 = e0 < end, v1 = e0 + 16u < end, v2 = e0 + 32u < end, v3 = e0 + 48u < end;
        int s0 = 0, s1 = 0, s2 = 0, s3 = 0;
        if (v0) s0 = __builtin_nontemporal_load(&srcA[e0]);
        if (v1) s1 = __builtin_nontemporal_load(&srcA[e0 + 16]);
        if (v2) s2 = __builtin_nontemporal_load(&srcA[e0 + 32]);
        if (v3) s3 = __builtin_nontemporal_load(&srcA[e0 + 48]);
        uint4 q0, q1, q2, q3;
        if (v0) q0 = *(const uint4*)(hs + ((size_t)s0 << 4));
        if (v1) q1 = *(const uint4*)(hs + ((size_t)s1 << 4));
        if (v2) q2 = *(const uint4*)(hs + ((size_t)s2 << 4));
        if (v3) q3 = *(const uint4*)(hs + ((size_t)s3 << 4));
        if (v0) ACC8(q0);
        if (v1) ACC8(q1);
        if (v2) ACC8(q2);
        if (v3) ACC8(q3);
    }
    // reduce-and-split butterfly: 15 shfl + 15 add, static reg indices only
    float r8[8];
#pragma unroll
    for (int k = 0; k < 8; k++) {
        float keep = (j & 8) ? acc[k + 8] : acc[k];
        float give = (j & 8) ? acc[k] : acc[k + 8];
        r8[k] = keep + __shfl_xor(give, 8, 16);
    }
    float r4[4];
#pragma unroll
    for (int k = 0; k < 4; k++) {
        float keep = (j & 4) ? r8[k + 4] : r8[k];
        float give = (j & 4) ? r8[k] : r8[k + 4];
        r4[k] = keep + __shfl_xor(give, 4, 16);
    }
    float r2[2];
#pragma unroll
    for (int k = 0; k < 2; k++) {
        float keep = (j & 2) ? r4[k + 2] : r4[k];
        float give = (j & 2) ? r4[k] : r4[k + 2];
        r2[k] = keep + __shfl_xor(give, 2, 16);
    }
    float keep = (j & 1) ? r2[1] : r2[0];
    float give = (j & 1) ? r2[0] : r2[1];
    float x = keep + __shfl_xor(give, 1, 16);
    return x + seed;
}

// ---------- layer1 gather + BN1/ReLU + GEMM2 ----------
__global__ __launch_bounds__(256) void k_gather1(const unsigned* __restrict__ rowptr,
                                                 const int* __restrict__ srcA,
                                                 const float* __restrict__ dis,
                                                 const unsigned char* __restrict__ hs1,
                                                 const float* __restrict__ b1,
                                                 const float* __restrict__ g1,
                                                 const float* __restrict__ be1,
                                                 const float* __restrict__ m1,
                                                 const float* __restrict__ v1,
                                                 const float* __restrict__ W2,
                                                 unsigned char* __restrict__ hs2) {
    __shared__ float W2s[D * D];
    int tid = threadIdx.x;
    if (tid < D * D) W2s[tid] = W2[tid];
    __syncthreads();
    int i = blockIdx.x * 16 + (tid >> 4);
    int j = tid & 15;
    float self = fp82f(hs1[((size_t)i << 4) + j]);
    float sum = gather_row_sum(rowptr, srcA, hs1, i, j, self);
    float di = dis[i];
    float tt = di * sum + b1[j];
    tt = fmaxf(tt, 0.f);
    float sc = g1[j] * rsqrtf(v1[j] + BNEPS);
    float x1 = (tt - m1[j]) * sc + be1[j];
    float acc = 0.f;
#pragma unroll
    for (int kk = 0; kk < D; kk++) {
        float v = __shfl(x1, kk, 16);
        acc += v * W2s[kk * D + j];
    }
    hs2[((size_t)i << 4) + j] = f2fp8(acc * di);
}

// ---------- layer2 gather + BN2/ReLU + fused pooling ----------
// block = 16 nodes; consecutive sorted batch ids span <=2 graphs in practice
// (min graph ~139 nodes). 4 LDS slots aggregate max/sum/count per graph; slots
// beyond 4 (statistically unreachable) fall back to direct global atomics.
__global__ __launch_bounds__(256) void k_gather2(const unsigned* __restrict__ rowptr,
                                                 const int* __restrict__ srcA,
                                                 const float* __restrict__ dis,
                                                 const unsigned char* __restrict__ hs2,
                                                 const float* __restrict__ b2,
                                                 const float* __restrict__ g2,
                                                 const float* __restrict__ be2,
                                                 const float* __restrict__ m2,
                                                 const float* __restrict__ v2,
                                                 const int* __restrict__ batch,
                                                 unsigned* __restrict__ gmaxT,
                                                 float* __restrict__ gsum,
                                                 unsigned* __restrict__ gcnt) {
    __shared__ unsigned smax[4 * D];
    __shared__ float ssum[4 * D];
    __shared__ unsigned scnt[4];
    int tid = threadIdx.x;
    if (tid < 4 * D) { smax[tid] = 0u; ssum[tid] = 0.f; }
    if (tid < 4) scnt[tid] = 0u;
    __syncthreads();
    int i = blockIdx.x * 16 + (tid >> 4);
    int j = tid & 15;
    float self = fp82f(hs2[((size_t)i << 4) + j]);
    float sum = gather_row_sum(rowptr, srcA, hs2, i, j, self);
    float tt = dis[i] * sum + b2[j];
    tt = fmaxf(tt, 0.f);
    float sc = g2[j] * rsqrtf(v2[j] + BNEPS);
    float xv = (tt - m2[j]) * sc + be2[j];
    int g = batch[i];
    int g0 = batch[blockIdx.x * 16];
    int slot = g - g0;
    if (slot < 4) {
        atomicMax(&smax[slot * D + j], f2ord(xv));
        atomicAdd(&ssum[slot * D + j], xv);
        if (j == 0) atomicAdd(&scnt[slot], 1u);
    } else {
        atomicMax(&gmaxT[(size_t)g * D + j], f2ord(xv));
        atomicAdd(&gsum[(size_t)g * D + j], xv);
        if (j == 0) atomicAdd(&gcnt[g], 1u);
    }
    __syncthreads();
    if (tid < 4 * D) {
        int s = tid >> 4, jj = tid & 15;
        if (scnt[s] > 0u) {
            int gg = g0 + s;
            atomicMax(&gmaxT[(size_t)gg * D + jj], smax[tid]);
            atomicAdd(&gsum[(size_t)gg * D + jj], ssum[tid]);
            if (jj == 0) atomicAdd(&gcnt[gg], scnt[s]);
        }
    }
}

// ---------- head ----------
__global__ __launch_bounds__(256) void k_head(const unsigned* __restrict__ gmaxT,
                                              const float* __restrict__ gsum,
                                              const unsigned* __restrict__ gcnt,
                                              const float* __restrict__ Wb,
                                              const float* __restrict__ bb,
                                              const float* __restrict__ Wm,
                                              const float* __restrict__ bm,
                                              float* __restrict__ out) {
    __shared__ float Wbs[32 * 16];
    __shared__ float bbs[16], Wms[16];
    __shared__ float bm0;
    int tid = threadIdx.x;
    for (int i = tid; i < 32 * 16; i += 256) Wbs[i] = Wb[i];
    if (tid < 16) { bbs[tid] = bb[tid]; Wms[tid] = Wm[tid]; }
    if (tid == 0) bm0 = bm[0];
    __syncthreads();
    int g = blockIdx.x * 256 + tid;
    if (g >= G) return;
    float in[32];
    float inv = 1.0f / (float)gcnt[g];
#pragma unroll
    for (int j = 0; j < D; j++) {
        in[j] = ord2f(gmaxT[(size_t)g * D + j]);
        in[16 + j] = gsum[(size_t)g * D + j] * inv;
    }
    float z = bm0;
#pragma unroll
    for (int j = 0; j < 16; j++) {
        float acc = bbs[j];
#pragma unroll
        for (int k = 0; k < 32; k++) acc += in[k] * Wbs[k * 16 + j];
        acc = fmaxf(acc, 0.f);
        z += acc * Wms[j];
    }
    out[g] = 1.0f / (1.0f + expf(-z));
}

extern "C" void kernel_launch(void* const* d_in, const int* in_sizes, int n_in,
                              void* d_out, int out_size, void* d_ws, size_t ws_size,
                              hipStream_t stream) {
    const float* x   = (const float*)d_in[0];
    const int* ei    = (const int*)d_in[1];
    const int* rowp  = ei;
    const int* colp  = ei + E;
    const int* batch = (const int*)d_in[2];
    const float* W1  = (const float*)d_in[3];
    const float* b1  = (const float*)d_in[4];
    const float* g1  = (const float*)d_in[5];
    const float* be1 = (const float*)d_in[6];
    const float* m1  = (const float*)d_in[7];
    const float* v1  = (const float*)d_in[8];
    const float* W2  = (const float*)d_in[9];
    const float* b2  = (const float*)d_in[10];
    const float* g2  = (const float*)d_in[11];
    const float* be2 = (const float*)d_in[12];
    const float* m2  = (const float*)d_in[13];
    const float* v2  = (const float*)d_in[14];
    const float* Wb  = (const float*)d_in[15];
    const float* bb  = (const float*)d_in[16];
    const float* Wm  = (const float*)d_in[17];
    const float* bm  = (const float*)d_in[18];
    float* out = (float*)d_out;

    char* ws = (char*)d_ws;
    int*      srcA   = (int*)     (ws);                // E i32            [0, 25.6M)
    unsigned* tmp    = (unsigned*)(ws + 25600000);     // E u32 packed     [25.6M, 51.2M)
    unsigned char* hs1 = (unsigned char*)(ws + 25600000); // N*D fp8 (3.2MB) — overlays tmp AFTER k_bsort
    unsigned char* hs2 = (unsigned char*)(ws + 28800000); // N*D fp8 (3.2MB) — also in dead tmp area
    unsigned* rowptr = (unsigned*)(ws + 51200000);     // (N+1) u32
    float*    dis    = (float*)   (ws + 52000016);     // N f32
    unsigned* bucketCnt  = (unsigned*)(ws + 52800016);
    unsigned* bucketBase = (unsigned*)(ws + 52801600);
    unsigned* cursorB    = (unsigned*)(ws + 52803200);
    unsigned* gmaxT  = (unsigned*)(ws + 52804800);
    float*    gsum   = (float*)   (ws + 52870336);
    unsigned* gcnt   = (unsigned*)(ws + 52935872);

    hipMemsetAsync(bucketCnt, 0, (NBKT + 1) * 4, stream);
    hipMemsetAsync(gmaxT, 0, (size_t)G * D * 4, stream);
    hipMemsetAsync(gsum, 0, (size_t)G * D * 4, stream);
    hipMemsetAsync(gcnt, 0, (size_t)G * 4, stream);

    k_hist<<<1024, 256, 0, stream>>>(colp, bucketCnt);
    k_bscan<<<1, 512, 0, stream>>>(bucketCnt, bucketBase, cursorB, rowptr);
    k_bin<<<BINB, 512, 0, stream>>>(rowp, colp, cursorB, tmp);
    k_bsort<<<NBKT, 512, 0, stream>>>(bucketBase, tmp, rowptr, dis, srcA);

    k_gemm1<<<512, 256, 0, stream>>>(x, W1, dis, hs1);

    k_gather1<<<N / 16, 256, 0, stream>>>(rowptr, srcA, dis, hs1,
                                          b1, g1, be1, m1, v1, W2, hs2);
    k_gather2<<<N / 16, 256, 0, stream>>>(rowptr, srcA, dis, hs2,
                                          b2, g2, be2, m2, v2,
                                          batch, gmaxT, gsum, gcnt);

    k_head<<<(G + 255) / 256, 256, 0, stream>>>(gmaxT, gsum, gcnt, Wb, bb, Wm, bm, out);
}

// Round 7
// 382.078 us; speedup vs baseline: 1.4533x; 1.1170x over previous
//
#include <hip/hip_runtime.h>
#include <math.h>

#define N   200000
#define E   6400000
#define IN_ 128
#define D   16
#define G   1024
#define BNEPS 1e-5f

#define BSH   9                      // 512 cols per bucket
#define NBKT  391                    // ceil(N / 512)
#define CH    8192                   // edges per k_bin block
#define BINB  782                    // ceil(E / CH)
#define BCAP  18432                  // padded region per bucket (mean 16384 + 16 sigma)

typedef _Float16 f16;
typedef __attribute__((ext_vector_type(8))) _Float16 f16x8;
typedef __attribute__((ext_vector_type(4))) float f32x4;
typedef __attribute__((ext_vector_type(2))) float f32x2;

// ---------- helpers ----------
__device__ __forceinline__ unsigned f2ord(float f) {
    unsigned b = __float_as_uint(f);
    return (b & 0x80000000u) ? ~b : (b | 0x80000000u);
}
__device__ __forceinline__ float ord2f(unsigned u) {
    return __uint_as_float((u & 0x80000000u) ? (u & 0x7FFFFFFFu) : ~u);
}
// f32 -> fp8 e4m3 (OCP on gfx950), single byte
__device__ __forceinline__ unsigned char f2fp8(float v) {
    return (unsigned char)(__builtin_amdgcn_cvt_pk_fp8_f32(v, v, 0, false) & 0xFF);
}
__device__ __forceinline__ float fp82f(unsigned char b) {
    return __builtin_amdgcn_cvt_f32_fp8((unsigned)b, 0);
}

// ---------- init: bucket cursors (padded layout) + pooling accumulators ----------
__global__ __launch_bounds__(256) void k_init(unsigned* __restrict__ cursorB,
                                              unsigned* __restrict__ gmaxT,
                                              float* __restrict__ gsum,
                                              unsigned* __restrict__ gcnt) {
    int t = blockIdx.x * 256 + threadIdx.x;
    if (t < NBKT) cursorB[t] = (unsigned)t * BCAP;
    if (t < G * D) { gmaxT[t] = 0u; gsum[t] = 0.f; }
    if (t < G) gcnt[t] = 0u;
}

// ---------- phase 1: bin edges into padded bucket regions ----------
__global__ __launch_bounds__(512) void k_bin(const int* __restrict__ row,
                                             const int* __restrict__ col,
                                             unsigned* __restrict__ cursorB,
                                             unsigned* __restrict__ tmp) {
    __shared__ unsigned hist[512];   // after scan phase: lbase
    __shared__ unsigned offs[512];   // inclusive scan (lbase[b+1])
    __shared__ unsigned lcur[512];
    __shared__ unsigned gbase[512];
    __shared__ unsigned sbuf[CH];    // 32 KB
    int tid = threadIdx.x;
    int base = blockIdx.x * CH;
    int cnt = min(CH, E - base);
    hist[tid] = 0u;
    __syncthreads();
    for (int i = tid; i < cnt; i += 512)
        atomicAdd(&hist[col[base + i] >> BSH], 1u);
    __syncthreads();
    offs[tid] = hist[tid];
    __syncthreads();
    for (int off = 1; off < 512; off <<= 1) {
        unsigned v = (tid >= off) ? offs[tid - off] : 0u;
        __syncthreads();
        offs[tid] += v;
        __syncthreads();
    }
    unsigned lb = (tid > 0) ? offs[tid - 1] : 0u;
    unsigned c0 = offs[tid] - lb;
    lcur[tid] = lb;
    hist[tid] = lb;   // hist now holds lbase
    if (tid < NBKT && c0) gbase[tid] = atomicAdd(&cursorB[tid], c0);
    __syncthreads();
    for (int i = tid; i < cnt; i += 512) {
        int c = col[base + i];
        int r = row[base + i];
        int b = c >> BSH;
        unsigned p = atomicAdd(&lcur[b], 1u);
        sbuf[p] = (unsigned)r | ((unsigned)(c & ((1 << BSH) - 1)) << 18);
    }
    __syncthreads();
    // bucket-major coalesced copy-out: one wave per bucket
    int wv = tid >> 6, ln = tid & 63;
    for (int b = wv; b < NBKT; b += 8) {
        unsigned l0 = hist[b], l1 = offs[b], gb = gbase[b];
        unsigned lim = (unsigned)(b + 1) * BCAP;   // never cross into next region
        for (unsigned i2 = l0 + ln; i2 < l1; i2 += 64) {
            unsigned dst = gb + (i2 - l0);
            if (dst < lim) tmp[dst] = sbuf[i2];
        }
    }
}

// ---------- phase 2: per-bucket counting sort (LDS-staged coalesced output) ----------
__global__ __launch_bounds__(512) void k_bsort(const unsigned* __restrict__ cursorB,
                                               const unsigned* __restrict__ tmp,
                                               unsigned* __restrict__ rowse,
                                               float* __restrict__ dis,
                                               int* __restrict__ srcA) {
    __shared__ unsigned cnt[512];
    __shared__ unsigned offs[512];
    __shared__ unsigned lcur[512];
    __shared__ unsigned sout[BCAP];  // 72 KB staging: scatter here, stream out coalesced
    int tid = threadIdx.x;
    int b = blockIdx.x;
    unsigned s0 = (unsigned)b * BCAP;
    unsigned s1 = min(cursorB[b], s0 + (unsigned)BCAP);
    cnt[tid] = 0u;
    __syncthreads();
    for (unsigned i = s0 + tid; i < s1; i += 512)
        atomicAdd(&cnt[tmp[i] >> 18], 1u);
    __syncthreads();
    offs[tid] = cnt[tid];
    __syncthreads();
    for (int off = 1; off < 512; off <<= 1) {
        unsigned v = (tid >= off) ? offs[tid - off] : 0u;
        __syncthreads();
        offs[tid] += v;
        __syncthreads();
    }
    unsigned excl = (tid > 0) ? offs[tid - 1] : 0u;
    int c = (b << BSH) + tid;
    if (c < N) {
        rowse[(size_t)c * 2]     = s0 + excl;       // start
        rowse[(size_t)c * 2 + 1] = s0 + offs[tid];  // end
        dis[c] = rsqrtf((float)cnt[tid] + 1.0f);
    }
    unsigned cap = s1 - s0;
    lcur[tid] = excl;                       // bucket-local offsets
    __syncthreads();
    for (unsigned i = s0 + tid; i < s1; i += 512) {
        unsigned p = tmp[i];
        unsigned pos = atomicAdd(&lcur[p >> 18], 1u);
        sout[pos] = p & 0x3FFFFu;
    }
    __syncthreads();
    // coalesced contiguous copy-out
    for (unsigned i = tid; i < cap; i += 512)
        srcA[s0 + i] = (int)sout[i];
}

// ---------- hs1 = fp8((x @ W1) * dis) via MFMA 16x16x32 f16 ----------
__global__ __launch_bounds__(256) void k_gemm1(const float* __restrict__ x,
                                               const float* __restrict__ W1,
                                               const float* __restrict__ dis,
                                               unsigned char* __restrict__ hs) {
    __shared__ f16 Wh[IN_ * D];
    int tid = threadIdx.x;
    for (int i = tid; i < IN_ * D; i += 256) Wh[i] = (f16)W1[i];
    __syncthreads();
    int lane = tid & 63;
    int wave = tid >> 6;
    int m = lane & 15, quad = lane >> 4;
    f16x8 bfrag[4];
#pragma unroll
    for (int s = 0; s < 4; s++)
#pragma unroll
        for (int jj = 0; jj < 8; jj++)
            bfrag[s][jj] = Wh[(s * 32 + quad * 8 + jj) * D + m];
    int gwave = blockIdx.x * 4 + wave;
    int nwaves = gridDim.x * 4;
    const int ntiles = N / 16;
    for (int t = gwave; t < ntiles; t += nwaves) {
        int n0 = t * 16;
        const float* xrow = x + (size_t)(n0 + m) * IN_ + quad * 8;
        f32x4 acc = {0.f, 0.f, 0.f, 0.f};
#pragma unroll
        for (int s = 0; s < 4; s++) {
            float4 lo = *(const float4*)(xrow + s * 32);
            float4 hi = *(const float4*)(xrow + s * 32 + 4);
            f16x8 a;
            a[0] = (f16)lo.x; a[1] = (f16)lo.y; a[2] = (f16)lo.z; a[3] = (f16)lo.w;
            a[4] = (f16)hi.x; a[5] = (f16)hi.y; a[6] = (f16)hi.z; a[7] = (f16)hi.w;
            acc = __builtin_amdgcn_mfma_f32_16x16x32_f16(a, bfrag[s], acc, 0, 0, 0);
        }
#pragma unroll
        for (int r = 0; r < 4; r++) {
            int rowi = n0 + quad * 4 + r;
            hs[(size_t)rowi * D + m] = f2fp8(acc[r] * dis[rowi]);
        }
    }
}

#define ACC8(q)                                                                           \
    {                                                                                     \
        f32x2 f;                                                                          \
        f = __builtin_amdgcn_cvt_pk_f32_fp8((q).x, false); acc[0] += f.x;  acc[1] += f.y; \
        f = __builtin_amdgcn_cvt_pk_f32_fp8((q).x, true);  acc[2] += f.x;  acc[3] += f.y; \
        f = __builtin_amdgcn_cvt_pk_f32_fp8((q).y, false); acc[4] += f.x;  acc[5] += f.y; \
        f = __builtin_amdgcn_cvt_pk_f32_fp8((q).y, true);  acc[6] += f.x;  acc[7] += f.y; \
        f = __builtin_amdgcn_cvt_pk_f32_fp8((q).z, false); acc[8] += f.x;  acc[9] += f.y; \
        f = __builtin_amdgcn_cvt_pk_f32_fp8((q).z, true);  acc[10] += f.x; acc[11] += f.y;\
        f = __builtin_amdgcn_cvt_pk_f32_fp8((q).w, false); acc[12] += f.x; acc[13] += f.y;\
        f = __builtin_amdgcn_cvt_pk_f32_fp8((q).w, true);  acc[14] += f.x; acc[15] += f.y;\
    }

// ---------- wide gather core (fp8 table, full-row-per-lane, 64 edges/iter) ----------
// 16 lanes per node. Each lane owns 4 edge slots (j, j+16, j+32, j+48): one
// iteration covers 64 edges with FOUR independent predicated uint4 gathers in
// flight per lane. Per-node [start,end) comes from the packed rowse uint2.
// Epilogue butterfly: lane j = feature j.
__device__ __forceinline__ float gather_row_sum(const unsigned* __restrict__ rowse,
                                                const int* __restrict__ srcA,
                                                const unsigned char* __restrict__ hs,
                                                int i, int j, float seed) {
    uint2 se = *(const uint2*)(rowse + ((size_t)i << 1));
    unsigned start = se.x, end = se.y;
    float acc[16];
#pragma unroll
    for (int k = 0; k < 16; k++) acc[k] = 0.f;
    for (unsigned base = start; base < end; base += 64) {
        unsigned e0 = base + (unsigned)j;
        bool v0 = e0 < end, v1 = e0 + 16u < end, v2 = e0 + 32u < end, v3 = e0 + 48u < end;
        int s0 = 0, s1 = 0, s2 = 0, s3 = 0;
        if (v0) s0 = __builtin_nontemporal_load(&srcA[e0]);
        if (v1) s1 = __builtin_nontemporal_load(&srcA[e0 + 16]);
        if (v2) s2 = __builtin_nontemporal_load(&srcA[e0 + 32]);
        if (v3) s3 = __builtin_nontemporal_load(&srcA[e0 + 48]);
        uint4 q0, q1, q2, q3;
        if (v0) q0 = *(const uint4*)(hs + ((size_t)s0 << 4));
        if (v1) q1 = *(const uint4*)(hs + ((size_t)s1 << 4));
        if (v2) q2 = *(const uint4*)(hs + ((size_t)s2 << 4));
        if (v3) q3 = *(const uint4*)(hs + ((size_t)s3 << 4));
        if (v0) ACC8(q0);
        if (v1) ACC8(q1);
        if (v2) ACC8(q2);
        if (v3) ACC8(q3);
    }
    // reduce-and-split butterfly: 15 shfl + 15 add, static reg indices only
    float r8[8];
#pragma unroll
    for (int k = 0; k < 8; k++) {
        float keep = (j & 8) ? acc[k + 8] : acc[k];
        float give = (j & 8) ? acc[k] : acc[k + 8];
        r8[k] = keep + __shfl_xor(give, 8, 16);
    }
    float r4[4];
#pragma unroll
    for (int k = 0; k < 4; k++) {
        float keep = (j & 4) ? r8[k + 4] : r8[k];
        float give = (j & 4) ? r8[k] : r8[k + 4];
        r4[k] = keep + __shfl_xor(give, 4, 16);
    }
    float r2[2];
#pragma unroll
    for (int k = 0; k < 2; k++) {
        float keep = (j & 2) ? r4[k + 2] : r4[k];
        float give = (j & 2) ? r4[k] : r4[k + 2];
        r2[k] = keep + __shfl_xor(give, 2, 16);
    }
    float keep = (j & 1) ? r2[1] : r2[0];
    float give = (j & 1) ? r2[0] : r2[1];
    float x = keep + __shfl_xor(give, 1, 16);
    return x + seed;
}

// ---------- layer1 gather + BN1/ReLU + GEMM2 ----------
__global__ __launch_bounds__(256) void k_gather1(const unsigned* __restrict__ rowse,
                                                 const int* __restrict__ srcA,
                                                 const float* __restrict__ dis,
                                                 const unsigned char* __restrict__ hs1,
                                                 const float* __restrict__ b1,
                                                 const float* __restrict__ g1,
                                                 const float* __restrict__ be1,
                                                 const float* __restrict__ m1,
                                                 const float* __restrict__ v1,
                                                 const float* __restrict__ W2,
                                                 unsigned char* __restrict__ hs2) {
    __shared__ float W2s[D * D];
    int tid = threadIdx.x;
    if (tid < D * D) W2s[tid] = W2[tid];
    __syncthreads();
    int i = blockIdx.x * 16 + (tid >> 4);
    int j = tid & 15;
    float self = fp82f(hs1[((size_t)i << 4) + j]);
    float sum = gather_row_sum(rowse, srcA, hs1, i, j, self);
    float di = dis[i];
    float tt = di * sum + b1[j];
    tt = fmaxf(tt, 0.f);
    float sc = g1[j] * rsqrtf(v1[j] + BNEPS);
    float x1 = (tt - m1[j]) * sc + be1[j];
    float acc = 0.f;
#pragma unroll
    for (int kk = 0; kk < D; kk++) {
        float v = __shfl(x1, kk, 16);
        acc += v * W2s[kk * D + j];
    }
    hs2[((size_t)i << 4) + j] = f2fp8(acc * di);
}

// ---------- layer2 gather + BN2/ReLU + fused pooling ----------
__global__ __launch_bounds__(256) void k_gather2(const unsigned* __restrict__ rowse,
                                                 const int* __restrict__ srcA,
                                                 const float* __restrict__ dis,
                                                 const unsigned char* __restrict__ hs2,
                                                 const float* __restrict__ b2,
                                                 const float* __restrict__ g2,
                                                 const float* __restrict__ be2,
                                                 const float* __restrict__ m2,
                                                 const float* __restrict__ v2,
                                                 const int* __restrict__ batch,
                                                 unsigned* __restrict__ gmaxT,
                                                 float* __restrict__ gsum,
                                                 unsigned* __restrict__ gcnt) {
    __shared__ unsigned smax[4 * D];
    __shared__ float ssum[4 * D];
    __shared__ unsigned scnt[4];
    int tid = threadIdx.x;
    if (tid < 4 * D) { smax[tid] = 0u; ssum[tid] = 0.f; }
    if (tid < 4) scnt[tid] = 0u;
    __syncthreads();
    int i = blockIdx.x * 16 + (tid >> 4);
    int j = tid & 15;
    float self = fp82f(hs2[((size_t)i << 4) + j]);
    float sum = gather_row_sum(rowse, srcA, hs2, i, j, self);
    float tt = dis[i] * sum + b2[j];
    tt = fmaxf(tt, 0.f);
    float sc = g2[j] * rsqrtf(v2[j] + BNEPS);
    float xv = (tt - m2[j]) * sc + be2[j];
    int g = batch[i];
    int g0 = batch[blockIdx.x * 16];
    int slot = g - g0;
    if (slot < 4) {
        atomicMax(&smax[slot * D + j], f2ord(xv));
        atomicAdd(&ssum[slot * D + j], xv);
        if (j == 0) atomicAdd(&scnt[slot], 1u);
    } else {
        atomicMax(&gmaxT[(size_t)g * D + j], f2ord(xv));
        atomicAdd(&gsum[(size_t)g * D + j], xv);
        if (j == 0) atomicAdd(&gcnt[g], 1u);
    }
    __syncthreads();
    if (tid < 4 * D) {
        int s = tid >> 4, jj = tid & 15;
        if (scnt[s] > 0u) {
            int gg = g0 + s;
            atomicMax(&gmaxT[(size_t)gg * D + jj], smax[tid]);
            atomicAdd(&gsum[(size_t)gg * D + jj], ssum[tid]);
            if (jj == 0) atomicAdd(&gcnt[gg], scnt[s]);
        }
    }
}

// ---------- head ----------
__global__ __launch_bounds__(256) void k_head(const unsigned* __restrict__ gmaxT,
                                              const float* __restrict__ gsum,
                                              const unsigned* __restrict__ gcnt,
                                              const float* __restrict__ Wb,
                                              const float* __restrict__ bb,
                                              const float* __restrict__ Wm,
                                              const float* __restrict__ bm,
                                              float* __restrict__ out) {
    __shared__ float Wbs[32 * 16];
    __shared__ float bbs[16], Wms[16];
    __shared__ float bm0;
    int tid = threadIdx.x;
    for (int i = tid; i < 32 * 16; i += 256) Wbs[i] = Wb[i];
    if (tid < 16) { bbs[tid] = bb[tid]; Wms[tid] = Wm[tid]; }
    if (tid == 0) bm0 = bm[0];
    __syncthreads();
    int g = blockIdx.x * 256 + tid;
    if (g >= G) return;
    float in[32];
    float inv = 1.0f / (float)gcnt[g];
#pragma unroll
    for (int j = 0; j < D; j++) {
        in[j] = ord2f(gmaxT[(size_t)g * D + j]);
        in[16 + j] = gsum[(size_t)g * D + j] * inv;
    }
    float z = bm0;
#pragma unroll
    for (int j = 0; j < 16; j++) {
        float acc = bbs[j];
#pragma unroll
        for (int k = 0; k < 32; k++) acc += in[k] * Wbs[k * 16 + j];
        acc = fmaxf(acc, 0.f);
        z += acc * Wms[j];
    }
    out[g] = 1.0f / (1.0f + expf(-z));
}

extern "C" void kernel_launch(void* const* d_in, const int* in_sizes, int n_in,
                              void* d_out, int out_size, void* d_ws, size_t ws_size,
                              hipStream_t stream) {
    const float* x   = (const float*)d_in[0];
    const int* ei    = (const int*)d_in[1];
    const int* rowp  = ei;
    const int* colp  = ei + E;
    const int* batch = (const int*)d_in[2];
    const float* W1  = (const float*)d_in[3];
    const float* b1  = (const float*)d_in[4];
    const float* g1  = (const float*)d_in[5];
    const float* be1 = (const float*)d_in[6];
    const float* m1  = (const float*)d_in[7];
    const float* v1  = (const float*)d_in[8];
    const float* W2  = (const float*)d_in[9];
    const float* b2  = (const float*)d_in[10];
    const float* g2  = (const float*)d_in[11];
    const float* be2 = (const float*)d_in[12];
    const float* m2  = (const float*)d_in[13];
    const float* v2  = (const float*)d_in[14];
    const float* Wb  = (const float*)d_in[15];
    const float* bb  = (const float*)d_in[16];
    const float* Wm  = (const float*)d_in[17];
    const float* bm  = (const float*)d_in[18];
    float* out = (float*)d_out;

    // padded layout: PADE = NBKT * BCAP entries
    const size_t PADE = (size_t)NBKT * BCAP;            // 7,206,912 entries
    char* ws = (char*)d_ws;
    int*      srcA   = (int*)     (ws);                 // PADE i32   [0, 28.83M)
    unsigned* tmp    = (unsigned*)(ws + 28827648);      // PADE u32   [28.83M, 57.66M)
    unsigned char* hs1 = (unsigned char*)(ws + 28827648); // N*D fp8 (3.2MB) — overlays tmp AFTER k_bsort
    unsigned char* hs2 = (unsigned char*)(ws + 32027648); // N*D fp8 (3.2MB) — also in dead tmp area
    unsigned* rowse  = (unsigned*)(ws + 57655296);      // N uint2 (start,end) 1.6MB
    float*    dis    = (float*)   (ws + 59255296);      // N f32
    unsigned* cursorB= (unsigned*)(ws + 60055296);      // NBKT u32
    unsigned* gmaxT  = (unsigned*)(ws + 60056896);      // G*D u32
    float*    gsum   = (float*)   (ws + 60122432);      // G*D f32
    unsigned* gcnt   = (unsigned*)(ws + 60187968);      // G u32
    (void)PADE;

    k_init<<<(G * D + 255) / 256, 256, 0, stream>>>(cursorB, gmaxT, gsum, gcnt);
    k_bin<<<BINB, 512, 0, stream>>>(rowp, colp, cursorB, tmp);
    k_bsort<<<NBKT, 512, 0, stream>>>(cursorB, tmp, rowse, dis, srcA);

    k_gemm1<<<512, 256, 0, stream>>>(x, W1, dis, hs1);

    k_gather1<<<N / 16, 256, 0, stream>>>(rowse, srcA, dis, hs1,
                                          b1, g1, be1, m1, v1, W2, hs2);
    k_gather2<<<N / 16, 256, 0, stream>>>(rowse, srcA, dis, hs2,
                                          b2, g2, be2, m2, v2,
                                          batch, gmaxT, gsum, gcnt);

    k_head<<<(G + 255) / 256, 256, 0, stream>>>(gmaxT, gsum, gcnt, Wb, bb, Wm, bm, out);
}